// Round 1
// baseline (5978.984 us; speedup 1.0000x reference)
//
#include <hip/hip_runtime.h>
#include <hip/hip_bf16.h>

namespace {

constexpr int NN = 20000;   // nodes
constexpr int NE = 320000;  // edges
constexpr int DI = 64;      // input node dim
constexpr int DE = 16;      // edge attr dim
constexpr int DM = 256;     // hidden dim
constexpr int DO = 10;      // out dim

// C[M,256] = op(A)@B + bias; op(A) = (1+eps)*A + A2 when COMBINE.
// RESID: C = C + (A@B + bias). RELU applied last.
template<bool RELU, bool RESID, bool COMBINE>
__global__ __launch_bounds__(256) void mm_kernel(
    const float* __restrict__ A, const float* __restrict__ A2,
    const float* __restrict__ eps_ptr, int eps_idx,
    const float* __restrict__ B, const float* __restrict__ bias,
    float* __restrict__ C, int M, int K)
{
  constexpr int BM = 128, BN = 64, BK = 32;
  __shared__ float Ast[BK][BM + 4];   // transposed A tile [k][m], stride 132 (16B-aligned rows)
  __shared__ float Bs[BK][BN];
  const int tid = threadIdx.x;
  const int rowBase = blockIdx.x * BM;
  const int colBase = blockIdx.y * BN;
  const int tx = tid & 15, ty = tid >> 4;

  float ep1 = 1.0f;
  if (COMBINE) ep1 += eps_ptr[eps_idx];

  float acc[8][4];
  #pragma unroll
  for (int i = 0; i < 8; ++i)
    #pragma unroll
    for (int j = 0; j < 4; ++j) acc[i][j] = 0.0f;

  const int ar = tid >> 3;        // 0..31
  const int ac = (tid & 7) * 4;   // 0..28
  const int br = tid >> 4;        // 0..15
  const int bc = (tid & 15) * 4;  // 0..60

  for (int k0 = 0; k0 < K; k0 += BK) {
    #pragma unroll
    for (int i = 0; i < 4; ++i) {
      const int row = ar + i * 32;
      const int grow = rowBase + row;
      float4 v = make_float4(0.f, 0.f, 0.f, 0.f);
      if (grow < M) {
        v = *reinterpret_cast<const float4*>(&A[(size_t)grow * K + k0 + ac]);
        if (COMBINE) {
          float4 w = *reinterpret_cast<const float4*>(&A2[(size_t)grow * K + k0 + ac]);
          v.x = ep1 * v.x + w.x; v.y = ep1 * v.y + w.y;
          v.z = ep1 * v.z + w.z; v.w = ep1 * v.w + w.w;
        }
      }
      Ast[ac + 0][row] = v.x; Ast[ac + 1][row] = v.y;
      Ast[ac + 2][row] = v.z; Ast[ac + 3][row] = v.w;
    }
    #pragma unroll
    for (int i = 0; i < 2; ++i) {
      const int row = br + i * 16;
      *reinterpret_cast<float4*>(&Bs[row][bc]) =
          *reinterpret_cast<const float4*>(&B[(size_t)(k0 + row) * DM + colBase + bc]);
    }
    __syncthreads();
    #pragma unroll
    for (int k = 0; k < BK; ++k) {
      const float4 a0 = *reinterpret_cast<const float4*>(&Ast[k][ty * 8]);
      const float4 a1 = *reinterpret_cast<const float4*>(&Ast[k][ty * 8 + 4]);
      const float4 bv = *reinterpret_cast<const float4*>(&Bs[k][tx * 4]);
      const float a[8] = {a0.x, a0.y, a0.z, a0.w, a1.x, a1.y, a1.z, a1.w};
      const float b[4] = {bv.x, bv.y, bv.z, bv.w};
      #pragma unroll
      for (int i = 0; i < 8; ++i)
        #pragma unroll
        for (int j = 0; j < 4; ++j)
          acc[i][j] += a[i] * b[j];
    }
    __syncthreads();
  }

  #pragma unroll
  for (int i = 0; i < 8; ++i) {
    const int grow = rowBase + ty * 8 + i;
    if (grow < M) {
      #pragma unroll
      for (int j = 0; j < 4; ++j) {
        const int gcol = colBase + tx * 4 + j;
        float v = acc[i][j] + bias[gcol];
        if (RESID) v += C[(size_t)grow * DM + gcol];
        if (RELU) v = fmaxf(v, 0.0f);
        C[(size_t)grow * DM + gcol] = v;
      }
    }
  }
}

// Fused GINE message + scatter:
//   for each edge j: msg[c] = relu(h[src[j]][c] + (edge_attr[j] @ W_ee)[c] + b_ee[c])
//   atomicAdd(agg[dst[j]][c], msg[c])
// One wave per edge; lane handles 4 channels. W_ee staged in LDS.
__global__ __launch_bounds__(256) void edge_kernel(
    const float* __restrict__ h, const float* __restrict__ eattr,
    const int* __restrict__ src, const int* __restrict__ dst,
    const float* __restrict__ Wee, const float* __restrict__ bee,
    float* __restrict__ agg, int E)
{
  __shared__ float Ws[DE * DM];  // 16 KiB
  const int tid = threadIdx.x;
  #pragma unroll
  for (int i = 0; i < 4; ++i)
    reinterpret_cast<float4*>(Ws)[tid + i * 256] =
        reinterpret_cast<const float4*>(Wee)[tid + i * 256];
  __syncthreads();

  const int lane = tid & 63;
  const int wave = tid >> 6;
  const int c4 = lane * 4;  // 0..252
  const float4 bv = *reinterpret_cast<const float4*>(&bee[c4]);

  for (int j = blockIdx.x * 4 + wave; j < E; j += gridDim.x * 4) {
    const int s = src[j];
    const int d = dst[j];
    const float4* eap = reinterpret_cast<const float4*>(&eattr[(size_t)j * DE]);
    const float4 e0 = eap[0], e1 = eap[1], e2 = eap[2], e3 = eap[3];
    const float ea[16] = {e0.x, e0.y, e0.z, e0.w, e1.x, e1.y, e1.z, e1.w,
                          e2.x, e2.y, e2.z, e2.w, e3.x, e3.y, e3.z, e3.w};
    const float4 hv = *reinterpret_cast<const float4*>(&h[(size_t)s * DM + c4]);
    float m0 = hv.x + bv.x, m1 = hv.y + bv.y, m2 = hv.z + bv.z, m3 = hv.w + bv.w;
    #pragma unroll
    for (int k = 0; k < DE; ++k) {
      const float4 w = *reinterpret_cast<const float4*>(&Ws[k * DM + c4]);
      m0 += ea[k] * w.x; m1 += ea[k] * w.y;
      m2 += ea[k] * w.z; m3 += ea[k] * w.w;
    }
    float* ap = &agg[(size_t)d * DM + c4];
    atomicAdd(ap + 0, fmaxf(m0, 0.f));
    atomicAdd(ap + 1, fmaxf(m1, 0.f));
    atomicAdd(ap + 2, fmaxf(m2, 0.f));
    atomicAdd(ap + 3, fmaxf(m3, 0.f));
  }
}

// out[M,10] = h[M,256] @ W[256,10] + b
__global__ __launch_bounds__(256) void head_kernel(
    const float* __restrict__ h, const float* __restrict__ W,
    const float* __restrict__ b, float* __restrict__ out, int M)
{
  __shared__ float Ws[DM * DO];
  const int tid = threadIdx.x;
  for (int i = tid; i < DM * DO; i += 256) Ws[i] = W[i];
  __syncthreads();
  const int r = tid >> 4;
  const int c = tid & 15;
  const int row = blockIdx.x * 16 + r;
  if (row < M && c < DO) {
    const float* hp = &h[(size_t)row * DM];
    float acc = 0.f;
    #pragma unroll 8
    for (int k = 0; k < DM; ++k) acc += hp[k] * Ws[k * DO + c];
    out[(size_t)row * DO + c] = acc + b[c];
  }
}

}  // namespace

extern "C" void kernel_launch(void* const* d_in, const int* in_sizes, int n_in,
                              void* d_out, int out_size, void* d_ws, size_t ws_size,
                              hipStream_t stream) {
  const float* x     = (const float*)d_in[0];
  const float* eattr = (const float*)d_in[1];
  const int*   eidx  = (const int*)d_in[2];
  const float* W_ne  = (const float*)d_in[3];
  const float* b_ne  = (const float*)d_in[4];
  const float* W_ee  = (const float*)d_in[5];
  const float* b_ee  = (const float*)d_in[6];
  const float* W_pre = (const float*)d_in[7];
  const float* b_pre = (const float*)d_in[8];
  const float* eps_a = (const float*)d_in[9];
  const float* W1_a  = (const float*)d_in[10];
  const float* b1_a  = (const float*)d_in[11];
  const float* W2_a  = (const float*)d_in[12];
  const float* b2_a  = (const float*)d_in[13];
  const float* eps_l = (const float*)d_in[14];
  const float* W1_l  = (const float*)d_in[15];
  const float* b1_l  = (const float*)d_in[16];
  const float* W2_l  = (const float*)d_in[17];
  const float* b2_l  = (const float*)d_in[18];
  const float* W_h   = (const float*)d_in[19];
  const float* b_h   = (const float*)d_in[20];

  const int* src = eidx;        // edge_index[0]
  const int* dst = eidx + NE;   // edge_index[1]

  float* h   = (float*)d_ws;                 // [NN, DM]
  float* t   = h + (size_t)NN * DM;          // [NN, DM]
  float* agg = t + (size_t)NN * DM;          // [NN, DM]

  const dim3 mmgrid((NN + 127) / 128, DM / 64);

  // FeatureEncoder node: t = x @ W_ne + b_ne
  mm_kernel<false, false, false><<<mmgrid, 256, 0, stream>>>(
      x, nullptr, nullptr, 0, W_ne, b_ne, t, NN, DI);
  // pre-MP: h = relu(t @ W_pre + b_pre)
  mm_kernel<true, false, false><<<mmgrid, 256, 0, stream>>>(
      t, nullptr, nullptr, 0, W_pre, b_pre, h, NN, DM);

  for (int layer = 0; layer < 5; ++layer) {
    const float* eps; int ei; const float *W1, *b1, *W2, *b2; bool resid;
    if (layer == 0) {
      eps = eps_a; ei = 0; W1 = W1_a; b1 = b1_a; W2 = W2_a; b2 = b2_a; resid = false;
    } else {
      const int i = layer - 1;
      eps = eps_l; ei = i;
      W1 = W1_l + (size_t)i * DM * DM; b1 = b1_l + (size_t)i * DM;
      W2 = W2_l + (size_t)i * DM * DM; b2 = b2_l + (size_t)i * DM;
      resid = true;
    }
    hipMemsetAsync(agg, 0, (size_t)NN * DM * sizeof(float), stream);
    edge_kernel<<<2048, 256, 0, stream>>>(h, eattr, src, dst, W_ee, b_ee, agg, NE);
    // t = relu(((1+eps)h + agg) @ W1 + b1)
    mm_kernel<true, false, true><<<mmgrid, 256, 0, stream>>>(
        h, agg, eps, ei, W1, b1, t, NN, DM);
    // h = [h +] t @ W2 + b2
    if (resid)
      mm_kernel<false, true, false><<<mmgrid, 256, 0, stream>>>(
          t, nullptr, nullptr, 0, W2, b2, h, NN, DM);
    else
      mm_kernel<false, false, false><<<mmgrid, 256, 0, stream>>>(
          t, nullptr, nullptr, 0, W2, b2, h, NN, DM);
  }

  head_kernel<<<(NN + 15) / 16, 256, 0, stream>>>(h, W_h, b_h, (float*)d_out, NN);
}

// Round 2
// 1157.300 us; speedup vs baseline: 5.1663x; 5.1663x over previous
//
#include <hip/hip_runtime.h>
#include <hip/hip_bf16.h>

namespace {

constexpr int NN = 20000;   // nodes
constexpr int NE = 320000;  // edges
constexpr int DI = 64;      // input node dim
constexpr int DE = 16;      // edge attr dim
constexpr int DM = 256;     // hidden dim
constexpr int DO = 10;      // out dim

// ---------------- CSR build (counting sort by dst) ----------------

__global__ __launch_bounds__(256) void hist_kernel(
    const int* __restrict__ dst, int* __restrict__ counts, int E)
{
  const int j = blockIdx.x * 256 + threadIdx.x;
  if (j < E) atomicAdd(&counts[dst[j]], 1);
}

// Single-block exclusive scan over counts[n] -> row_ptr[n+1] and cursor[n].
__global__ __launch_bounds__(1024) void scan_kernel(
    const int* __restrict__ counts, int* __restrict__ row_ptr,
    int* __restrict__ cursor, int n)
{
  __shared__ int partial[1024];
  const int t = threadIdx.x;
  const int chunk = (n + 1023) / 1024;
  const int beg = t * chunk;
  const int end = min(beg + chunk, n);
  int s = 0;
  for (int i = beg; i < end; ++i) s += counts[i];
  partial[t] = s;
  __syncthreads();
  // Hillis-Steele inclusive scan
  for (int off = 1; off < 1024; off <<= 1) {
    const int v = (t >= off) ? partial[t - off] : 0;
    __syncthreads();
    partial[t] += v;
    __syncthreads();
  }
  int base = (t == 0) ? 0 : partial[t - 1];
  for (int i = beg; i < end; ++i) {
    const int c = counts[i];
    row_ptr[i] = base;
    cursor[i] = base;
    base += c;
  }
  if (t == 1023) row_ptr[n] = partial[1023];
}

__global__ __launch_bounds__(256) void scatter_kernel(
    const int* __restrict__ src, const int* __restrict__ dst,
    int* __restrict__ cursor, int* __restrict__ esrc,
    int* __restrict__ eid, int E)
{
  const int j = blockIdx.x * 256 + threadIdx.x;
  if (j < E) {
    const int p = atomicAdd(&cursor[dst[j]], 1);
    esrc[p] = src[j];
    eid[p] = j;
  }
}

// ---------------- fused GINE gather ----------------
// out[i] = (1+eps)*h[i] + sum_{p in [row_ptr[i],row_ptr[i+1])}
//            relu(h[esrc[p]] + eattr[eid[p]] @ W_ee + b_ee)
// One wave per node; lane owns 4 channels. W_ee staged in LDS.
__global__ __launch_bounds__(256) void gather_kernel(
    const float* __restrict__ h, const float* __restrict__ eattr,
    const int* __restrict__ row_ptr, const int* __restrict__ esrc,
    const int* __restrict__ eid,
    const float* __restrict__ Wee, const float* __restrict__ bee,
    const float* __restrict__ eps_ptr, int eps_idx,
    float* __restrict__ out, int n)
{
  __shared__ float Ws[DE * DM];  // 16 KiB
  const int tid = threadIdx.x;
  #pragma unroll
  for (int i = 0; i < 4; ++i)
    reinterpret_cast<float4*>(Ws)[tid + i * 256] =
        reinterpret_cast<const float4*>(Wee)[tid + i * 256];
  __syncthreads();

  const int lane = tid & 63;
  const int wave = tid >> 6;
  const int c4 = lane * 4;
  const float4 bv = *reinterpret_cast<const float4*>(&bee[c4]);
  const float ep1 = 1.0f + eps_ptr[eps_idx];

  for (int i = blockIdx.x * 4 + wave; i < n; i += gridDim.x * 4) {
    const int beg = row_ptr[i];
    const int end = row_ptr[i + 1];
    float a0 = 0.f, a1 = 0.f, a2 = 0.f, a3 = 0.f;
    for (int p = beg; p < end; ++p) {
      const int s = esrc[p];
      const int j = eid[p];
      const float4* eap = reinterpret_cast<const float4*>(&eattr[(size_t)j * DE]);
      const float4 e0 = eap[0], e1 = eap[1], e2 = eap[2], e3 = eap[3];
      const float ea[16] = {e0.x, e0.y, e0.z, e0.w, e1.x, e1.y, e1.z, e1.w,
                            e2.x, e2.y, e2.z, e2.w, e3.x, e3.y, e3.z, e3.w};
      const float4 hv = *reinterpret_cast<const float4*>(&h[(size_t)s * DM + c4]);
      float m0 = hv.x + bv.x, m1 = hv.y + bv.y;
      float m2 = hv.z + bv.z, m3 = hv.w + bv.w;
      #pragma unroll
      for (int k = 0; k < DE; ++k) {
        const float4 w = *reinterpret_cast<const float4*>(&Ws[k * DM + c4]);
        m0 += ea[k] * w.x; m1 += ea[k] * w.y;
        m2 += ea[k] * w.z; m3 += ea[k] * w.w;
      }
      a0 += fmaxf(m0, 0.f); a1 += fmaxf(m1, 0.f);
      a2 += fmaxf(m2, 0.f); a3 += fmaxf(m3, 0.f);
    }
    const float4 hv = *reinterpret_cast<const float4*>(&h[(size_t)i * DM + c4]);
    float4 o;
    o.x = ep1 * hv.x + a0; o.y = ep1 * hv.y + a1;
    o.z = ep1 * hv.z + a2; o.w = ep1 * hv.w + a3;
    *reinterpret_cast<float4*>(&out[(size_t)i * DM + c4]) = o;
  }
}

// ---------------- dense matmuls ----------------
// C[M,256] = A@B + bias; RESID: C += old C; RELU applied last.
template<bool RELU, bool RESID>
__global__ __launch_bounds__(256) void mm_kernel(
    const float* __restrict__ A,
    const float* __restrict__ B, const float* __restrict__ bias,
    float* __restrict__ C, int M, int K)
{
  constexpr int BM = 128, BN = 64, BK = 32;
  __shared__ float Ast[BK][BM + 4];
  __shared__ float Bs[BK][BN];
  const int tid = threadIdx.x;
  const int rowBase = blockIdx.x * BM;
  const int colBase = blockIdx.y * BN;
  const int tx = tid & 15, ty = tid >> 4;

  float acc[8][4];
  #pragma unroll
  for (int i = 0; i < 8; ++i)
    #pragma unroll
    for (int j = 0; j < 4; ++j) acc[i][j] = 0.0f;

  const int ar = tid >> 3;
  const int ac = (tid & 7) * 4;
  const int br = tid >> 4;
  const int bc = (tid & 15) * 4;

  for (int k0 = 0; k0 < K; k0 += BK) {
    #pragma unroll
    for (int i = 0; i < 4; ++i) {
      const int row = ar + i * 32;
      const int grow = rowBase + row;
      float4 v = make_float4(0.f, 0.f, 0.f, 0.f);
      if (grow < M)
        v = *reinterpret_cast<const float4*>(&A[(size_t)grow * K + k0 + ac]);
      Ast[ac + 0][row] = v.x; Ast[ac + 1][row] = v.y;
      Ast[ac + 2][row] = v.z; Ast[ac + 3][row] = v.w;
    }
    #pragma unroll
    for (int i = 0; i < 2; ++i) {
      const int row = br + i * 16;
      *reinterpret_cast<float4*>(&Bs[row][bc]) =
          *reinterpret_cast<const float4*>(&B[(size_t)(k0 + row) * DM + colBase + bc]);
    }
    __syncthreads();
    #pragma unroll
    for (int k = 0; k < BK; ++k) {
      const float4 a0 = *reinterpret_cast<const float4*>(&Ast[k][ty * 8]);
      const float4 a1 = *reinterpret_cast<const float4*>(&Ast[k][ty * 8 + 4]);
      const float4 bv = *reinterpret_cast<const float4*>(&Bs[k][tx * 4]);
      const float a[8] = {a0.x, a0.y, a0.z, a0.w, a1.x, a1.y, a1.z, a1.w};
      const float b[4] = {bv.x, bv.y, bv.z, bv.w};
      #pragma unroll
      for (int i = 0; i < 8; ++i)
        #pragma unroll
        for (int j = 0; j < 4; ++j)
          acc[i][j] += a[i] * b[j];
    }
    __syncthreads();
  }

  #pragma unroll
  for (int i = 0; i < 8; ++i) {
    const int grow = rowBase + ty * 8 + i;
    if (grow < M) {
      #pragma unroll
      for (int j = 0; j < 4; ++j) {
        const int gcol = colBase + tx * 4 + j;
        float v = acc[i][j] + bias[gcol];
        if (RESID) v += C[(size_t)grow * DM + gcol];
        if (RELU) v = fmaxf(v, 0.0f);
        C[(size_t)grow * DM + gcol] = v;
      }
    }
  }
}

// out[M,10] = h[M,256] @ W[256,10] + b
__global__ __launch_bounds__(256) void head_kernel(
    const float* __restrict__ h, const float* __restrict__ W,
    const float* __restrict__ b, float* __restrict__ out, int M)
{
  __shared__ float Ws[DM * DO];
  const int tid = threadIdx.x;
  for (int i = tid; i < DM * DO; i += 256) Ws[i] = W[i];
  __syncthreads();
  const int r = tid >> 4;
  const int c = tid & 15;
  const int row = blockIdx.x * 16 + r;
  if (row < M && c < DO) {
    const float* hp = &h[(size_t)row * DM];
    float acc = 0.f;
    #pragma unroll 8
    for (int k = 0; k < DM; ++k) acc += hp[k] * Ws[k * DO + c];
    out[(size_t)row * DO + c] = acc + b[c];
  }
}

}  // namespace

extern "C" void kernel_launch(void* const* d_in, const int* in_sizes, int n_in,
                              void* d_out, int out_size, void* d_ws, size_t ws_size,
                              hipStream_t stream) {
  const float* x     = (const float*)d_in[0];
  const float* eattr = (const float*)d_in[1];
  const int*   eidx  = (const int*)d_in[2];
  const float* W_ne  = (const float*)d_in[3];
  const float* b_ne  = (const float*)d_in[4];
  const float* W_ee  = (const float*)d_in[5];
  const float* b_ee  = (const float*)d_in[6];
  const float* W_pre = (const float*)d_in[7];
  const float* b_pre = (const float*)d_in[8];
  const float* eps_a = (const float*)d_in[9];
  const float* W1_a  = (const float*)d_in[10];
  const float* b1_a  = (const float*)d_in[11];
  const float* W2_a  = (const float*)d_in[12];
  const float* b2_a  = (const float*)d_in[13];
  const float* eps_l = (const float*)d_in[14];
  const float* W1_l  = (const float*)d_in[15];
  const float* b1_l  = (const float*)d_in[16];
  const float* W2_l  = (const float*)d_in[17];
  const float* b2_l  = (const float*)d_in[18];
  const float* W_h   = (const float*)d_in[19];
  const float* b_h   = (const float*)d_in[20];

  const int* src = eidx;        // edge_index[0]
  const int* dst = eidx + NE;   // edge_index[1]

  // workspace layout
  float* h    = (float*)d_ws;                  // [NN, DM]
  float* t    = h + (size_t)NN * DM;           // [NN, DM]
  float* agg  = t + (size_t)NN * DM;           // [NN, DM] (combined input to MLP)
  int* counts  = (int*)(agg + (size_t)NN * DM);  // [NN]
  int* row_ptr = counts + NN;                    // [NN+1]
  int* cursor  = row_ptr + NN + 1;               // [NN]
  int* esrc    = cursor + NN;                    // [NE]
  int* eid     = esrc + NE;                      // [NE]

  // ---- build CSR by dst (once per call) ----
  hipMemsetAsync(counts, 0, NN * sizeof(int), stream);
  hist_kernel<<<(NE + 255) / 256, 256, 0, stream>>>(dst, counts, NE);
  scan_kernel<<<1, 1024, 0, stream>>>(counts, row_ptr, cursor, NN);
  scatter_kernel<<<(NE + 255) / 256, 256, 0, stream>>>(src, dst, cursor, esrc, eid, NE);

  const dim3 mmgrid((NN + 127) / 128, DM / 64);

  // FeatureEncoder node: t = x @ W_ne + b_ne
  mm_kernel<false, false><<<mmgrid, 256, 0, stream>>>(x, W_ne, b_ne, t, NN, DI);
  // pre-MP: h = relu(t @ W_pre + b_pre)
  mm_kernel<true, false><<<mmgrid, 256, 0, stream>>>(t, W_pre, b_pre, h, NN, DM);

  for (int layer = 0; layer < 5; ++layer) {
    const float* eps; int ei; const float *W1, *b1, *W2, *b2; bool resid;
    if (layer == 0) {
      eps = eps_a; ei = 0; W1 = W1_a; b1 = b1_a; W2 = W2_a; b2 = b2_a; resid = false;
    } else {
      const int i = layer - 1;
      eps = eps_l; ei = i;
      W1 = W1_l + (size_t)i * DM * DM; b1 = b1_l + (size_t)i * DM;
      W2 = W2_l + (size_t)i * DM * DM; b2 = b2_l + (size_t)i * DM;
      resid = true;
    }
    // agg = (1+eps)*h + sum relu(h[src] + e) — gather over CSR, no atomics
    gather_kernel<<<(NN + 3) / 4, 256, 0, stream>>>(
        h, eattr, row_ptr, esrc, eid, W_ee, b_ee, eps, ei, agg, NN);
    // t = relu(agg @ W1 + b1)
    mm_kernel<true, false><<<mmgrid, 256, 0, stream>>>(agg, W1, b1, t, NN, DM);
    // h = [h +] t @ W2 + b2
    if (resid)
      mm_kernel<false, true><<<mmgrid, 256, 0, stream>>>(t, W2, b2, h, NN, DM);
    else
      mm_kernel<false, false><<<mmgrid, 256, 0, stream>>>(t, W2, b2, h, NN, DM);
  }

  head_kernel<<<(NN + 15) / 16, 256, 0, stream>>>(h, W_h, b_h, (float*)d_out, NN);
}

// Round 4
// 1055.880 us; speedup vs baseline: 5.6626x; 1.0961x over previous
//
#include <hip/hip_runtime.h>
#include <hip/hip_bf16.h>

namespace {

constexpr int NN = 20000;   // nodes
constexpr int NE = 320000;  // edges
constexpr int DI = 64;      // input node dim
constexpr int DE = 16;      // edge attr dim
constexpr int DM = 256;     // hidden dim
constexpr int DO = 10;      // out dim

// weight-plane offsets: mat 0 = W_ne (64*256), mats 1..11 = 256*256 each
// 1=W_pre, 2=W1_a, 3=W2_a, 4..7=W1_l[i], 8..11=W2_l[i]
__host__ __device__ constexpr size_t woff(int m) {
  return m == 0 ? 0 : (size_t)16384 + (size_t)(m - 1) * 65536;
}
constexpr size_t WTOTAL = 16384 + 11 * 65536;  // 737280 elements per plane

typedef __attribute__((ext_vector_type(8))) short s16x8;
typedef __attribute__((ext_vector_type(4))) float f32x4;

__device__ inline unsigned short f2bf(float x) {
  union { float f; unsigned u; } c; c.f = x;
  unsigned r = (c.u + 0x7FFFu + ((c.u >> 16) & 1u)) >> 16;
  return (unsigned short)r;
}
__device__ inline float bf2f(unsigned short h) {
  union { unsigned u; float f; } c; c.u = ((unsigned)h) << 16;
  return c.f;
}

// ---------------- CSR build (counting sort by dst) ----------------

__global__ __launch_bounds__(256) void hist_kernel(
    const int* __restrict__ dst, int* __restrict__ counts, int E)
{
  const int j = blockIdx.x * 256 + threadIdx.x;
  if (j < E) atomicAdd(&counts[dst[j]], 1);
}

__global__ __launch_bounds__(1024) void scan_kernel(
    const int* __restrict__ counts, int* __restrict__ row_ptr,
    int* __restrict__ cursor, int n)
{
  __shared__ int partial[1024];
  const int t = threadIdx.x;
  const int chunk = (n + 1023) / 1024;
  const int beg = t * chunk;
  const int end = min(beg + chunk, n);
  int s = 0;
  for (int i = beg; i < end; ++i) s += counts[i];
  partial[t] = s;
  __syncthreads();
  for (int off = 1; off < 1024; off <<= 1) {
    const int v = (t >= off) ? partial[t - off] : 0;
    __syncthreads();
    partial[t] += v;
    __syncthreads();
  }
  int base = (t == 0) ? 0 : partial[t - 1];
  for (int i = beg; i < end; ++i) {
    const int c = counts[i];
    row_ptr[i] = base;
    cursor[i] = base;
    base += c;
  }
  if (t == 1023) row_ptr[n] = partial[1023];
}

__global__ __launch_bounds__(256) void scatter_kernel(
    const int* __restrict__ src, const int* __restrict__ dst,
    int* __restrict__ cursor, int2* __restrict__ epack, int E)
{
  const int j = blockIdx.x * 256 + threadIdx.x;
  if (j < E) {
    const int p = atomicAdd(&cursor[dst[j]], 1);
    epack[p] = make_int2(src[j], j);
  }
}

// ---------------- weight preprocessing: transpose + bf16 hi/lo split ----
// For weight W[K,256] produce Wt_hi/Wt_lo[256][K] (n-major, k-contig).
__global__ __launch_bounds__(256) void convertW_kernel(
    const float* __restrict__ W_ne, const float* __restrict__ W_pre,
    const float* __restrict__ W1_a, const float* __restrict__ W2_a,
    const float* __restrict__ W1_l, const float* __restrict__ W2_l,
    unsigned short* __restrict__ hi, unsigned short* __restrict__ lo)
{
  const int mat = blockIdx.y;
  const float* src;
  int K = 256;
  if (mat == 0)      { src = W_ne;  K = 64; }
  else if (mat == 1) { src = W_pre; }
  else if (mat == 2) { src = W1_a; }
  else if (mat == 3) { src = W2_a; }
  else if (mat < 8)  { src = W1_l + (size_t)(mat - 4) * 65536; }
  else               { src = W2_l + (size_t)(mat - 8) * 65536; }
  const size_t off = woff(mat);

  const int ntiles = (K >> 6) * 4;
  const int t = blockIdx.x;
  if (t >= ntiles) return;
  const int tk = t % (K >> 6);
  const int tn = t / (K >> 6);

  __shared__ float tile[64][65];
  const int tid = threadIdx.x;
  const int c = tid & 63;
  const int rg = tid >> 6;
  for (int i = 0; i < 16; ++i) {
    const int r = rg + i * 4;
    tile[r][c] = src[(size_t)(tk * 64 + r) * 256 + tn * 64 + c];
  }
  __syncthreads();
  const int k = tk * 64 + c;
  for (int i = 0; i < 16; ++i) {
    const int nn = rg + i * 4;
    const int n = tn * 64 + nn;
    const float x = tile[c][nn];
    const unsigned short hh = f2bf(x);
    hi[off + (size_t)n * K + k] = hh;
    lo[off + (size_t)n * K + k] = f2bf(x - bf2f(hh));
  }
}

// ---------------- MFMA matmul, split-bf16 (3-term), fp32 in/out ----------
// C[M,256] = A[M,K] @ B[K,256] + bias ; RESID: += old C ; RELU last.
// B passed pre-transposed/split: Bth/Btl[256][K] bf16 (n-major, k-contig).
template<bool RELU, bool RESID>
__global__ __launch_bounds__(256) void mm_mfma(
    const float* __restrict__ A, const unsigned short* __restrict__ Bth,
    const unsigned short* __restrict__ Btl, const float* __restrict__ bias,
    float* __restrict__ C, int M, int K)
{
  __shared__ unsigned short Ah[128 * 64], Al[128 * 64];
  __shared__ unsigned short Bh[128 * 64], Bl[128 * 64];
  const int tid = threadIdx.x;
  const int lane = tid & 63, wid = tid >> 6;
  const int wr = wid >> 1, wc = wid & 1;
  const int l15 = lane & 15, l4 = lane >> 4;
  const int rowBase = blockIdx.x * 128, colBase = blockIdx.y * 128;

  f32x4 acc[4][4];
  #pragma unroll
  for (int i = 0; i < 4; ++i)
    #pragma unroll
    for (int j = 0; j < 4; ++j) acc[i][j] = (f32x4){0.f, 0.f, 0.f, 0.f};

  const int nk = K >> 6;
  for (int ks = 0; ks < nk; ++ks) {
    // stage A: fp32 -> bf16 hi/lo, XOR-swizzled 16B chunks
    #pragma unroll
    for (int i = 0; i < 4; ++i) {
      const int u = tid + i * 256;
      const int row = u >> 3, kc = u & 7;
      const int grow = rowBase + row;
      float4 v0 = make_float4(0.f, 0.f, 0.f, 0.f), v1 = v0;
      if (grow < M) {
        const float* p = A + (size_t)grow * K + ks * 64 + kc * 8;
        v0 = *reinterpret_cast<const float4*>(p);
        v1 = *reinterpret_cast<const float4*>(p + 4);
      }
      const float xs[8] = {v0.x, v0.y, v0.z, v0.w, v1.x, v1.y, v1.z, v1.w};
      s16x8 hv, lv;
      #pragma unroll
      for (int j = 0; j < 8; ++j) {
        const unsigned short hh = f2bf(xs[j]);
        hv[j] = (short)hh;
        lv[j] = (short)f2bf(xs[j] - bf2f(hh));
      }
      const int chunk = row * 8 + (kc ^ (row & 7));
      ((s16x8*)Ah)[chunk] = hv;
      ((s16x8*)Al)[chunk] = lv;
    }
    // stage B: already bf16 hi/lo, just swizzle into LDS
    #pragma unroll
    for (int i = 0; i < 4; ++i) {
      const int u = tid + i * 256;
      const int n = u >> 3, kc = u & 7;
      const size_t g = (size_t)(colBase + n) * K + ks * 64 + kc * 8;
      const int chunk = n * 8 + (kc ^ (n & 7));
      ((s16x8*)Bh)[chunk] = *reinterpret_cast<const s16x8*>(Bth + g);
      ((s16x8*)Bl)[chunk] = *reinterpret_cast<const s16x8*>(Btl + g);
    }
    __syncthreads();
    #pragma unroll
    for (int sub = 0; sub < 2; ++sub) {
      const int kc = sub * 4 + l4;
      s16x8 ah[4], al[4], bh[4], bl[4];
      #pragma unroll
      for (int mi = 0; mi < 4; ++mi) {
        const int r = wr * 64 + mi * 16 + l15;
        const int ch = r * 8 + (kc ^ (r & 7));
        ah[mi] = ((const s16x8*)Ah)[ch];
        al[mi] = ((const s16x8*)Al)[ch];
      }
      #pragma unroll
      for (int ni = 0; ni < 4; ++ni) {
        const int r = wc * 64 + ni * 16 + l15;
        const int ch = r * 8 + (kc ^ (r & 7));
        bh[ni] = ((const s16x8*)Bh)[ch];
        bl[ni] = ((const s16x8*)Bl)[ch];
      }
      #pragma unroll
      for (int mi = 0; mi < 4; ++mi)
        #pragma unroll
        for (int ni = 0; ni < 4; ++ni) {
          acc[mi][ni] = __builtin_amdgcn_mfma_f32_16x16x32_bf16(ah[mi], bh[ni], acc[mi][ni], 0, 0, 0);
          acc[mi][ni] = __builtin_amdgcn_mfma_f32_16x16x32_bf16(al[mi], bh[ni], acc[mi][ni], 0, 0, 0);
          acc[mi][ni] = __builtin_amdgcn_mfma_f32_16x16x32_bf16(ah[mi], bl[ni], acc[mi][ni], 0, 0, 0);
        }
    }
    __syncthreads();
  }

  #pragma unroll
  for (int ni = 0; ni < 4; ++ni) {
    const int gcol = colBase + wc * 64 + ni * 16 + l15;
    const float bv = bias[gcol];
    #pragma unroll
    for (int mi = 0; mi < 4; ++mi) {
      const int rbase = rowBase + wr * 64 + mi * 16 + l4 * 4;
      #pragma unroll
      for (int r = 0; r < 4; ++r) {
        const int grow = rbase + r;
        if (grow < M) {
          float v = acc[mi][ni][r] + bv;
          if (RESID) v += C[(size_t)grow * DM + gcol];
          if (RELU) v = fmaxf(v, 0.f);
          C[(size_t)grow * DM + gcol] = v;
        }
      }
    }
  }
}

// ---------------- fused GINE gather, W_ee in registers ----------------
__global__ __launch_bounds__(256) void gather_kernel(
    const float* __restrict__ h, const float* __restrict__ eattr,
    const int* __restrict__ row_ptr, const int2* __restrict__ epack,
    const float* __restrict__ Wee, const float* __restrict__ bee,
    const float* __restrict__ eps_ptr, int eps_idx,
    float* __restrict__ out, int n)
{
  const int tid = threadIdx.x;
  const int lane = tid & 63, wave = tid >> 6;
  const int c4 = lane * 4;
  float4 w[16];
  #pragma unroll
  for (int k = 0; k < 16; ++k)
    w[k] = *reinterpret_cast<const float4*>(&Wee[k * DM + c4]);
  const float4 bv = *reinterpret_cast<const float4*>(&bee[c4]);
  const float ep1 = 1.0f + eps_ptr[eps_idx];

  for (int i = blockIdx.x * 4 + wave; i < n; i += gridDim.x * 4) {
    const int beg = row_ptr[i], end = row_ptr[i + 1];
    const float4 hself = *reinterpret_cast<const float4*>(&h[(size_t)i * DM + c4]);
    float a0 = 0.f, a1 = 0.f, a2 = 0.f, a3 = 0.f;
    float4 hv = hself, e0 = bv, e1 = bv, e2 = bv, e3 = bv;
    if (beg < end) {
      const int2 sj = epack[beg];
      hv = *reinterpret_cast<const float4*>(&h[(size_t)sj.x * DM + c4]);
      const float4* ep = reinterpret_cast<const float4*>(&eattr[(size_t)sj.y * DE]);
      e0 = ep[0]; e1 = ep[1]; e2 = ep[2]; e3 = ep[3];
    }
    for (int p = beg; p < end; ++p) {
      float4 hvn = hv, f0 = e0, f1 = e1, f2 = e2, f3 = e3;
      if (p + 1 < end) {  // wave-uniform: prefetch next edge
        const int2 sj = epack[p + 1];
        hvn = *reinterpret_cast<const float4*>(&h[(size_t)sj.x * DM + c4]);
        const float4* ep = reinterpret_cast<const float4*>(&eattr[(size_t)sj.y * DE]);
        f0 = ep[0]; f1 = ep[1]; f2 = ep[2]; f3 = ep[3];
      }
      float m0 = hv.x + bv.x, m1 = hv.y + bv.y;
      float m2 = hv.z + bv.z, m3 = hv.w + bv.w;
      const float ea[16] = {e0.x, e0.y, e0.z, e0.w, e1.x, e1.y, e1.z, e1.w,
                            e2.x, e2.y, e2.z, e2.w, e3.x, e3.y, e3.z, e3.w};
      #pragma unroll
      for (int k = 0; k < 16; ++k) {
        m0 += ea[k] * w[k].x; m1 += ea[k] * w[k].y;
        m2 += ea[k] * w[k].z; m3 += ea[k] * w[k].w;
      }
      a0 += fmaxf(m0, 0.f); a1 += fmaxf(m1, 0.f);
      a2 += fmaxf(m2, 0.f); a3 += fmaxf(m3, 0.f);
      hv = hvn; e0 = f0; e1 = f1; e2 = f2; e3 = f3;
    }
    float4 o;
    o.x = ep1 * hself.x + a0; o.y = ep1 * hself.y + a1;
    o.z = ep1 * hself.z + a2; o.w = ep1 * hself.w + a3;
    *reinterpret_cast<float4*>(&out[(size_t)i * DM + c4]) = o;
  }
}

// out[M,10] = h[M,256] @ W[256,10] + b
__global__ __launch_bounds__(256) void head_kernel(
    const float* __restrict__ h, const float* __restrict__ W,
    const float* __restrict__ b, float* __restrict__ out, int M)
{
  __shared__ float Ws[DM * DO];
  const int tid = threadIdx.x;
  for (int i = tid; i < DM * DO; i += 256) Ws[i] = W[i];
  __syncthreads();
  const int r = tid >> 4;
  const int c = tid & 15;
  const int row = blockIdx.x * 16 + r;
  if (row < M && c < DO) {
    const float* hp = &h[(size_t)row * DM];
    float acc = 0.f;
    #pragma unroll 8
    for (int k = 0; k < DM; ++k) acc += hp[k] * Ws[k * DO + c];
    out[(size_t)row * DO + c] = acc + b[c];
  }
}

}  // namespace

extern "C" void kernel_launch(void* const* d_in, const int* in_sizes, int n_in,
                              void* d_out, int out_size, void* d_ws, size_t ws_size,
                              hipStream_t stream) {
  const float* x     = (const float*)d_in[0];
  const float* eattr = (const float*)d_in[1];
  const int*   eidx  = (const int*)d_in[2];
  const float* W_ne  = (const float*)d_in[3];
  const float* b_ne  = (const float*)d_in[4];
  const float* W_ee  = (const float*)d_in[5];
  const float* b_ee  = (const float*)d_in[6];
  const float* W_pre = (const float*)d_in[7];
  const float* b_pre = (const float*)d_in[8];
  const float* eps_a = (const float*)d_in[9];
  const float* W1_a  = (const float*)d_in[10];
  const float* b1_a  = (const float*)d_in[11];
  const float* W2_a  = (const float*)d_in[12];
  const float* b2_a  = (const float*)d_in[13];
  const float* eps_l = (const float*)d_in[14];
  const float* W1_l  = (const float*)d_in[15];
  const float* b1_l  = (const float*)d_in[16];
  const float* W2_l  = (const float*)d_in[17];
  const float* b2_l  = (const float*)d_in[18];
  const float* W_h   = (const float*)d_in[19];
  const float* b_h   = (const float*)d_in[20];

  const int* src = eidx;
  const int* dst = eidx + NE;

  // workspace layout (16B-aligned sections)
  float* h   = (float*)d_ws;                       // [NN,DM]
  float* t   = h + (size_t)NN * DM;                // [NN,DM]
  float* agg = t + (size_t)NN * DM;                // [NN,DM]
  int2* epack = (int2*)(agg + (size_t)NN * DM);    // [NE]
  unsigned short* wt_hi = (unsigned short*)(epack + NE);
  unsigned short* wt_lo = wt_hi + WTOTAL;
  int* counts  = (int*)(wt_lo + WTOTAL);
  int* row_ptr = counts + NN;
  int* cursor  = row_ptr + NN + 1;

  // ---- CSR build ----
  hipMemsetAsync(counts, 0, NN * sizeof(int), stream);
  hist_kernel<<<(NE + 255) / 256, 256, 0, stream>>>(dst, counts, NE);
  scan_kernel<<<1, 1024, 0, stream>>>(counts, row_ptr, cursor, NN);
  scatter_kernel<<<(NE + 255) / 256, 256, 0, stream>>>(src, dst, cursor, epack, NE);

  // ---- weight preprocessing (transpose + hi/lo split) ----
  convertW_kernel<<<dim3(16, 12), 256, 0, stream>>>(
      W_ne, W_pre, W1_a, W2_a, W1_l, W2_l, wt_hi, wt_lo);

  const dim3 mmgrid((NN + 127) / 128, 2);

  // encoder: t = x @ W_ne + b_ne   (K=64)
  mm_mfma<false, false><<<mmgrid, 256, 0, stream>>>(
      x, wt_hi + woff(0), wt_lo + woff(0), b_ne, t, NN, DI);
  // pre-MP: h = relu(t @ W_pre + b_pre)
  mm_mfma<true, false><<<mmgrid, 256, 0, stream>>>(
      t, wt_hi + woff(1), wt_lo + woff(1), b_pre, h, NN, DM);

  for (int layer = 0; layer < 5; ++layer) {
    const float* eps; int ei; const float *b1, *b2; size_t o1, o2; bool resid;
    if (layer == 0) {
      eps = eps_a; ei = 0; b1 = b1_a; b2 = b2_a;
      o1 = woff(2); o2 = woff(3); resid = false;
    } else {
      const int i = layer - 1;
      eps = eps_l; ei = i;
      b1 = b1_l + (size_t)i * DM; b2 = b2_l + (size_t)i * DM;
      o1 = woff(4 + i); o2 = woff(8 + i); resid = true;
    }
    gather_kernel<<<(NN + 3) / 4, 256, 0, stream>>>(
        h, eattr, row_ptr, epack, W_ee, b_ee, eps, ei, agg, NN);
    mm_mfma<true, false><<<mmgrid, 256, 0, stream>>>(
        agg, wt_hi + o1, wt_lo + o1, b1, t, NN, DM);
    if (resid)
      mm_mfma<false, true><<<mmgrid, 256, 0, stream>>>(
          t, wt_hi + o2, wt_lo + o2, b2, h, NN, DM);
    else
      mm_mfma<false, false><<<mmgrid, 256, 0, stream>>>(
          t, wt_hi + o2, wt_lo + o2, b2, h, NN, DM);
  }

  head_kernel<<<(NN + 15) / 16, 256, 0, stream>>>(h, W_h, b_h, (float*)d_out, NN);
}

// Round 5
// 1002.771 us; speedup vs baseline: 5.9625x; 1.0530x over previous
//
#include <hip/hip_runtime.h>
#include <hip/hip_bf16.h>

namespace {

constexpr int NN = 20000;   // nodes
constexpr int NE = 320000;  // edges
constexpr int DI = 64;      // input node dim
constexpr int DE = 16;      // edge attr dim
constexpr int DM = 256;     // hidden dim
constexpr int DO = 10;      // out dim

// weight-plane offsets: mat 0 = W_ne (64*256), mats 1..11 = 256*256 each
// 1=W_pre, 2=W1_a, 3=W2_a, 4..7=W1_l[i], 8..11=W2_l[i]
__host__ __device__ constexpr size_t woff(int m) {
  return m == 0 ? 0 : (size_t)16384 + (size_t)(m - 1) * 65536;
}
constexpr size_t WTOTAL = 16384 + 11 * 65536;

typedef __attribute__((ext_vector_type(8))) short s16x8;
typedef __attribute__((ext_vector_type(4))) float f32x4;

__device__ inline unsigned short f2bf(float x) {
  union { float f; unsigned u; } c; c.f = x;
  unsigned r = (c.u + 0x7FFFu + ((c.u >> 16) & 1u)) >> 16;
  return (unsigned short)r;
}
__device__ inline float bf2f(unsigned short h) {
  union { unsigned u; float f; } c; c.u = ((unsigned)h) << 16;
  return c.f;
}

// ---------------- CSR build (counting sort by dst) ----------------

__global__ __launch_bounds__(256) void hist_kernel(
    const int* __restrict__ dst, int* __restrict__ counts, int E)
{
  const int j = blockIdx.x * 256 + threadIdx.x;
  if (j < E) atomicAdd(&counts[dst[j]], 1);
}

__global__ __launch_bounds__(1024) void scan_kernel(
    const int* __restrict__ counts, int* __restrict__ row_ptr,
    int* __restrict__ cursor, int n)
{
  __shared__ int partial[1024];
  const int t = threadIdx.x;
  const int chunk = (n + 1023) / 1024;
  const int beg = t * chunk;
  const int end = min(beg + chunk, n);
  int s = 0;
  for (int i = beg; i < end; ++i) s += counts[i];
  partial[t] = s;
  __syncthreads();
  for (int off = 1; off < 1024; off <<= 1) {
    const int v = (t >= off) ? partial[t - off] : 0;
    __syncthreads();
    partial[t] += v;
    __syncthreads();
  }
  int base = (t == 0) ? 0 : partial[t - 1];
  for (int i = beg; i < end; ++i) {
    const int c = counts[i];
    row_ptr[i] = base;
    cursor[i] = base;
    base += c;
  }
  if (t == 1023) row_ptr[n] = partial[1023];
}

// CSR scatter: also materialize edge attrs in CSR order as bf16.
__global__ __launch_bounds__(256) void scatter_kernel(
    const int* __restrict__ src, const int* __restrict__ dst,
    const float* __restrict__ eattr, int* __restrict__ cursor,
    int* __restrict__ esrc, unsigned short* __restrict__ ea16, int E)
{
  const int j = blockIdx.x * 256 + threadIdx.x;
  if (j < E) {
    const int p = atomicAdd(&cursor[dst[j]], 1);
    esrc[p] = src[j];
    const float4* ep = reinterpret_cast<const float4*>(&eattr[(size_t)j * DE]);
    const float4 e0 = ep[0], e1 = ep[1], e2 = ep[2], e3 = ep[3];
    const float ea[16] = {e0.x, e0.y, e0.z, e0.w, e1.x, e1.y, e1.z, e1.w,
                          e2.x, e2.y, e2.z, e2.w, e3.x, e3.y, e3.z, e3.w};
    s16x8 v0, v1;
    #pragma unroll
    for (int k = 0; k < 8; ++k) {
      v0[k] = (short)f2bf(ea[k]);
      v1[k] = (short)f2bf(ea[8 + k]);
    }
    s16x8* op = reinterpret_cast<s16x8*>(&ea16[(size_t)p * DE]);
    op[0] = v0; op[1] = v1;
  }
}

// ---------------- weight preprocessing: transpose + bf16 hi/lo split ----
__global__ __launch_bounds__(256) void convertW_kernel(
    const float* __restrict__ W_ne, const float* __restrict__ W_pre,
    const float* __restrict__ W1_a, const float* __restrict__ W2_a,
    const float* __restrict__ W1_l, const float* __restrict__ W2_l,
    unsigned short* __restrict__ hi, unsigned short* __restrict__ lo)
{
  const int mat = blockIdx.y;
  const float* src;
  int K = 256;
  if (mat == 0)      { src = W_ne;  K = 64; }
  else if (mat == 1) { src = W_pre; }
  else if (mat == 2) { src = W1_a; }
  else if (mat == 3) { src = W2_a; }
  else if (mat < 8)  { src = W1_l + (size_t)(mat - 4) * 65536; }
  else               { src = W2_l + (size_t)(mat - 8) * 65536; }
  const size_t off = woff(mat);

  const int ntiles = (K >> 6) * 4;
  const int t = blockIdx.x;
  if (t >= ntiles) return;
  const int tk = t % (K >> 6);
  const int tn = t / (K >> 6);

  __shared__ float tile[64][65];
  const int tid = threadIdx.x;
  const int c = tid & 63;
  const int rg = tid >> 6;
  for (int i = 0; i < 16; ++i) {
    const int r = rg + i * 4;
    tile[r][c] = src[(size_t)(tk * 64 + r) * 256 + tn * 64 + c];
  }
  __syncthreads();
  const int k = tk * 64 + c;
  for (int i = 0; i < 16; ++i) {
    const int nn = rg + i * 4;
    const int n = tn * 64 + nn;
    const float x = tile[c][nn];
    const unsigned short hh = f2bf(x);
    hi[off + (size_t)n * K + k] = hh;
    lo[off + (size_t)n * K + k] = f2bf(x - bf2f(hh));
  }
}

// ---------------- MFMA matmul, split-bf16 (3-term), fp32 in/out ----------
// HOUT: also emit bf16 copy of the result (for the gather path).
template<bool RELU, bool RESID, bool HOUT>
__global__ __launch_bounds__(256) void mm_mfma(
    const float* __restrict__ A, const unsigned short* __restrict__ Bth,
    const unsigned short* __restrict__ Btl, const float* __restrict__ bias,
    float* __restrict__ C, unsigned short* __restrict__ H16, int M, int K)
{
  __shared__ unsigned short Ah[128 * 64], Al[128 * 64];
  __shared__ unsigned short Bh[128 * 64], Bl[128 * 64];
  const int tid = threadIdx.x;
  const int lane = tid & 63, wid = tid >> 6;
  const int wr = wid >> 1, wc = wid & 1;
  const int l15 = lane & 15, l4 = lane >> 4;
  const int rowBase = blockIdx.x * 128, colBase = blockIdx.y * 128;

  f32x4 acc[4][4];
  #pragma unroll
  for (int i = 0; i < 4; ++i)
    #pragma unroll
    for (int j = 0; j < 4; ++j) acc[i][j] = (f32x4){0.f, 0.f, 0.f, 0.f};

  const int nk = K >> 6;
  for (int ks = 0; ks < nk; ++ks) {
    #pragma unroll
    for (int i = 0; i < 4; ++i) {
      const int u = tid + i * 256;
      const int row = u >> 3, kc = u & 7;
      const int grow = rowBase + row;
      float4 v0 = make_float4(0.f, 0.f, 0.f, 0.f), v1 = v0;
      if (grow < M) {
        const float* p = A + (size_t)grow * K + ks * 64 + kc * 8;
        v0 = *reinterpret_cast<const float4*>(p);
        v1 = *reinterpret_cast<const float4*>(p + 4);
      }
      const float xs[8] = {v0.x, v0.y, v0.z, v0.w, v1.x, v1.y, v1.z, v1.w};
      s16x8 hv, lv;
      #pragma unroll
      for (int j = 0; j < 8; ++j) {
        const unsigned short hh = f2bf(xs[j]);
        hv[j] = (short)hh;
        lv[j] = (short)f2bf(xs[j] - bf2f(hh));
      }
      const int chunk = row * 8 + (kc ^ (row & 7));
      ((s16x8*)Ah)[chunk] = hv;
      ((s16x8*)Al)[chunk] = lv;
    }
    #pragma unroll
    for (int i = 0; i < 4; ++i) {
      const int u = tid + i * 256;
      const int n = u >> 3, kc = u & 7;
      const size_t g = (size_t)(colBase + n) * K + ks * 64 + kc * 8;
      const int chunk = n * 8 + (kc ^ (n & 7));
      ((s16x8*)Bh)[chunk] = *reinterpret_cast<const s16x8*>(Bth + g);
      ((s16x8*)Bl)[chunk] = *reinterpret_cast<const s16x8*>(Btl + g);
    }
    __syncthreads();
    #pragma unroll
    for (int sub = 0; sub < 2; ++sub) {
      const int kc = sub * 4 + l4;
      s16x8 ah[4], al[4], bh[4], bl[4];
      #pragma unroll
      for (int mi = 0; mi < 4; ++mi) {
        const int r = wr * 64 + mi * 16 + l15;
        const int ch = r * 8 + (kc ^ (r & 7));
        ah[mi] = ((const s16x8*)Ah)[ch];
        al[mi] = ((const s16x8*)Al)[ch];
      }
      #pragma unroll
      for (int ni = 0; ni < 4; ++ni) {
        const int r = wc * 64 + ni * 16 + l15;
        const int ch = r * 8 + (kc ^ (r & 7));
        bh[ni] = ((const s16x8*)Bh)[ch];
        bl[ni] = ((const s16x8*)Bl)[ch];
      }
      #pragma unroll
      for (int mi = 0; mi < 4; ++mi)
        #pragma unroll
        for (int ni = 0; ni < 4; ++ni) {
          acc[mi][ni] = __builtin_amdgcn_mfma_f32_16x16x32_bf16(ah[mi], bh[ni], acc[mi][ni], 0, 0, 0);
          acc[mi][ni] = __builtin_amdgcn_mfma_f32_16x16x32_bf16(al[mi], bh[ni], acc[mi][ni], 0, 0, 0);
          acc[mi][ni] = __builtin_amdgcn_mfma_f32_16x16x32_bf16(ah[mi], bl[ni], acc[mi][ni], 0, 0, 0);
        }
    }
    __syncthreads();
  }

  #pragma unroll
  for (int ni = 0; ni < 4; ++ni) {
    const int gcol = colBase + wc * 64 + ni * 16 + l15;
    const float bv = bias[gcol];
    #pragma unroll
    for (int mi = 0; mi < 4; ++mi) {
      const int rbase = rowBase + wr * 64 + mi * 16 + l4 * 4;
      #pragma unroll
      for (int r = 0; r < 4; ++r) {
        const int grow = rbase + r;
        if (grow < M) {
          float v = acc[mi][ni][r] + bv;
          if (RESID) v += C[(size_t)grow * DM + gcol];
          if (RELU) v = fmaxf(v, 0.f);
          C[(size_t)grow * DM + gcol] = v;
          if (HOUT) H16[(size_t)grow * DM + gcol] = f2bf(v);
        }
      }
    }
  }
}

// ---------------- fused GINE gather v3 ----------------
// Messages read bf16 h and CSR-streamed bf16 edge attrs; backbone stays fp32.
// W_ee in registers; ~4 nodes per wave to amortize setup.
__global__ __launch_bounds__(256) void gather_kernel(
    const float* __restrict__ h, const unsigned short* __restrict__ h16,
    const int* __restrict__ row_ptr, const int* __restrict__ esrc,
    const unsigned short* __restrict__ ea16,
    const float* __restrict__ Wee, const float* __restrict__ bee,
    const float* __restrict__ eps_ptr, int eps_idx,
    float* __restrict__ out, int n)
{
  const int tid = threadIdx.x;
  const int lane = tid & 63, wave = tid >> 6;
  const int c4 = lane * 4;
  float4 w[16];
  #pragma unroll
  for (int k = 0; k < 16; ++k)
    w[k] = *reinterpret_cast<const float4*>(&Wee[k * DM + c4]);
  const float4 bv = *reinterpret_cast<const float4*>(&bee[c4]);
  const float ep1 = 1.0f + eps_ptr[eps_idx];
  const int stride = gridDim.x * 4;

  for (int i = blockIdx.x * 4 + wave; i < n; i += stride) {
    const int beg = row_ptr[i], end = row_ptr[i + 1];
    float a0 = 0.f, a1 = 0.f, a2 = 0.f, a3 = 0.f;
    for (int p = beg; p < end; ++p) {
      const int s = esrc[p];
      const ushort4 hv = *reinterpret_cast<const ushort4*>(&h16[(size_t)s * DM + c4]);
      const s16x8* eap = reinterpret_cast<const s16x8*>(&ea16[(size_t)p * DE]);
      const s16x8 ew0 = eap[0], ew1 = eap[1];
      float m0 = bf2f(hv.x) + bv.x, m1 = bf2f(hv.y) + bv.y;
      float m2 = bf2f(hv.z) + bv.z, m3 = bf2f(hv.w) + bv.w;
      float ea[16];
      #pragma unroll
      for (int k = 0; k < 8; ++k) {
        ea[k] = bf2f((unsigned short)ew0[k]);
        ea[8 + k] = bf2f((unsigned short)ew1[k]);
      }
      #pragma unroll
      for (int k = 0; k < 16; ++k) {
        m0 += ea[k] * w[k].x; m1 += ea[k] * w[k].y;
        m2 += ea[k] * w[k].z; m3 += ea[k] * w[k].w;
      }
      a0 += fmaxf(m0, 0.f); a1 += fmaxf(m1, 0.f);
      a2 += fmaxf(m2, 0.f); a3 += fmaxf(m3, 0.f);
    }
    const float4 hself = *reinterpret_cast<const float4*>(&h[(size_t)i * DM + c4]);
    float4 o;
    o.x = ep1 * hself.x + a0; o.y = ep1 * hself.y + a1;
    o.z = ep1 * hself.z + a2; o.w = ep1 * hself.w + a3;
    *reinterpret_cast<float4*>(&out[(size_t)i * DM + c4]) = o;
  }
}

// out[M,10] = h[M,256] @ W[256,10] + b
__global__ __launch_bounds__(256) void head_kernel(
    const float* __restrict__ h, const float* __restrict__ W,
    const float* __restrict__ b, float* __restrict__ out, int M)
{
  __shared__ float Ws[DM * DO];
  const int tid = threadIdx.x;
  for (int i = tid; i < DM * DO; i += 256) Ws[i] = W[i];
  __syncthreads();
  const int r = tid >> 4;
  const int c = tid & 15;
  const int row = blockIdx.x * 16 + r;
  if (row < M && c < DO) {
    const float* hp = &h[(size_t)row * DM];
    float acc = 0.f;
    #pragma unroll 8
    for (int k = 0; k < DM; ++k) acc += hp[k] * Ws[k * DO + c];
    out[(size_t)row * DO + c] = acc + b[c];
  }
}

}  // namespace

extern "C" void kernel_launch(void* const* d_in, const int* in_sizes, int n_in,
                              void* d_out, int out_size, void* d_ws, size_t ws_size,
                              hipStream_t stream) {
  const float* x     = (const float*)d_in[0];
  const float* eattr = (const float*)d_in[1];
  const int*   eidx  = (const int*)d_in[2];
  const float* W_ne  = (const float*)d_in[3];
  const float* b_ne  = (const float*)d_in[4];
  const float* W_ee  = (const float*)d_in[5];
  const float* b_ee  = (const float*)d_in[6];
  const float* W_pre = (const float*)d_in[7];
  const float* b_pre = (const float*)d_in[8];
  const float* eps_a = (const float*)d_in[9];
  const float* W1_a  = (const float*)d_in[10];
  const float* b1_a  = (const float*)d_in[11];
  const float* W2_a  = (const float*)d_in[12];
  const float* b2_a  = (const float*)d_in[13];
  const float* eps_l = (const float*)d_in[14];
  const float* W1_l  = (const float*)d_in[15];
  const float* b1_l  = (const float*)d_in[16];
  const float* W2_l  = (const float*)d_in[17];
  const float* b2_l  = (const float*)d_in[18];
  const float* W_h   = (const float*)d_in[19];
  const float* b_h   = (const float*)d_in[20];

  const int* src = eidx;
  const int* dst = eidx + NE;

  // workspace layout (16B-aligned sections)
  float* h   = (float*)d_ws;                        // [NN,DM] f32
  float* t   = h + (size_t)NN * DM;                 // [NN,DM] f32
  float* agg = t + (size_t)NN * DM;                 // [NN,DM] f32
  unsigned short* h16  = (unsigned short*)(agg + (size_t)NN * DM);  // [NN,DM] bf16
  unsigned short* ea16 = h16 + (size_t)NN * DM;     // [NE,DE] bf16
  unsigned short* wt_hi = ea16 + (size_t)NE * DE;   // [WTOTAL]
  unsigned short* wt_lo = wt_hi + WTOTAL;           // [WTOTAL]
  int* esrc    = (int*)(wt_lo + WTOTAL);            // [NE]
  int* counts  = esrc + NE;                         // [NN]
  int* row_ptr = counts + NN;                       // [NN+1]
  int* cursor  = row_ptr + NN + 1;                  // [NN]

  // ---- CSR build ----
  hipMemsetAsync(counts, 0, NN * sizeof(int), stream);
  hist_kernel<<<(NE + 255) / 256, 256, 0, stream>>>(dst, counts, NE);
  scan_kernel<<<1, 1024, 0, stream>>>(counts, row_ptr, cursor, NN);
  scatter_kernel<<<(NE + 255) / 256, 256, 0, stream>>>(
      src, dst, eattr, cursor, esrc, ea16, NE);

  // ---- weight preprocessing ----
  convertW_kernel<<<dim3(16, 12), 256, 0, stream>>>(
      W_ne, W_pre, W1_a, W2_a, W1_l, W2_l, wt_hi, wt_lo);

  const dim3 mmgrid((NN + 127) / 128, 2);

  // encoder: t = x @ W_ne + b_ne   (K=64)
  mm_mfma<false, false, false><<<mmgrid, 256, 0, stream>>>(
      x, wt_hi + woff(0), wt_lo + woff(0), b_ne, t, nullptr, NN, DI);
  // pre-MP: h = relu(t @ W_pre + b_pre)  (+ bf16 copy)
  mm_mfma<true, false, true><<<mmgrid, 256, 0, stream>>>(
      t, wt_hi + woff(1), wt_lo + woff(1), b_pre, h, h16, NN, DM);

  for (int layer = 0; layer < 5; ++layer) {
    const float* eps; int ei; const float *b1, *b2; size_t o1, o2; bool resid;
    if (layer == 0) {
      eps = eps_a; ei = 0; b1 = b1_a; b2 = b2_a;
      o1 = woff(2); o2 = woff(3); resid = false;
    } else {
      const int i = layer - 1;
      eps = eps_l; ei = i;
      b1 = b1_l + (size_t)i * DM; b2 = b2_l + (size_t)i * DM;
      o1 = woff(4 + i); o2 = woff(8 + i); resid = true;
    }
    gather_kernel<<<1280, 256, 0, stream>>>(
        h, h16, row_ptr, esrc, ea16, W_ee, b_ee, eps, ei, agg, NN);
    mm_mfma<true, false, false><<<mmgrid, 256, 0, stream>>>(
        agg, wt_hi + o1, wt_lo + o1, b1, t, nullptr, NN, DM);
    if (resid)
      mm_mfma<false, true, true><<<mmgrid, 256, 0, stream>>>(
          t, wt_hi + o2, wt_lo + o2, b2, h, h16, NN, DM);
    else
      mm_mfma<false, false, true><<<mmgrid, 256, 0, stream>>>(
          t, wt_hi + o2, wt_lo + o2, b2, h, h16, NN, DM);
  }

  head_kernel<<<(NN + 15) / 16, 256, 0, stream>>>(h, W_h, b_h, (float*)d_out, NN);
}

// Round 6
// 757.666 us; speedup vs baseline: 7.8913x; 1.3235x over previous
//
#include <hip/hip_runtime.h>
#include <hip/hip_bf16.h>

namespace {

constexpr int NN = 20000;   // nodes
constexpr int NE = 320000;  // edges
constexpr int DI = 64;      // input node dim
constexpr int DE = 16;      // edge attr dim
constexpr int DM = 256;     // hidden dim
constexpr int DO = 10;      // out dim

// weight-plane offsets: mat 0 = W_ne (64*256), mats 1..11 = 256*256 each
__host__ __device__ constexpr size_t woff(int m) {
  return m == 0 ? 0 : (size_t)16384 + (size_t)(m - 1) * 65536;
}
constexpr size_t WTOTAL = 16384 + 11 * 65536;

typedef __attribute__((ext_vector_type(8))) short s16x8;
typedef __attribute__((ext_vector_type(4))) float f32x4;

__device__ inline unsigned short f2bf(float x) {
  union { float f; unsigned u; } c; c.f = x;
  unsigned r = (c.u + 0x7FFFu + ((c.u >> 16) & 1u)) >> 16;
  return (unsigned short)r;
}
__device__ inline float bf2f(unsigned short h) {
  union { unsigned u; float f; } c; c.u = ((unsigned)h) << 16;
  return c.f;
}

// ---------------- CSR build (counting sort by dst) ----------------

__global__ __launch_bounds__(256) void hist_kernel(
    const int* __restrict__ dst, int* __restrict__ counts, int E)
{
  const int j = blockIdx.x * 256 + threadIdx.x;
  if (j < E) atomicAdd(&counts[dst[j]], 1);
}

__global__ __launch_bounds__(1024) void scan_kernel(
    const int* __restrict__ counts, int* __restrict__ row_ptr,
    int* __restrict__ cursor, int n)
{
  __shared__ int partial[1024];
  const int t = threadIdx.x;
  const int chunk = (n + 1023) / 1024;
  const int beg = t * chunk;
  const int end = min(beg + chunk, n);
  int s = 0;
  for (int i = beg; i < end; ++i) s += counts[i];
  partial[t] = s;
  __syncthreads();
  for (int off = 1; off < 1024; off <<= 1) {
    const int v = (t >= off) ? partial[t - off] : 0;
    __syncthreads();
    partial[t] += v;
    __syncthreads();
  }
  int base = (t == 0) ? 0 : partial[t - 1];
  for (int i = beg; i < end; ++i) {
    const int c = counts[i];
    row_ptr[i] = base;
    cursor[i] = base;
    base += c;
  }
  if (t == 1023) row_ptr[n] = partial[1023];
}

// CSR scatter: edge attrs re-ordered into CSR order as bf16.
__global__ __launch_bounds__(256) void scatter_kernel(
    const int* __restrict__ src, const int* __restrict__ dst,
    const float* __restrict__ eattr, int* __restrict__ cursor,
    int* __restrict__ esrc, unsigned short* __restrict__ ea16, int E)
{
  const int j = blockIdx.x * 256 + threadIdx.x;
  if (j < E) {
    const int p = atomicAdd(&cursor[dst[j]], 1);
    esrc[p] = src[j];
    const float4* ep = reinterpret_cast<const float4*>(&eattr[(size_t)j * DE]);
    const float4 e0 = ep[0], e1 = ep[1], e2 = ep[2], e3 = ep[3];
    const float ea[16] = {e0.x, e0.y, e0.z, e0.w, e1.x, e1.y, e1.z, e1.w,
                          e2.x, e2.y, e2.z, e2.w, e3.x, e3.y, e3.z, e3.w};
    s16x8 v0, v1;
    #pragma unroll
    for (int k = 0; k < 8; ++k) {
      v0[k] = (short)f2bf(ea[k]);
      v1[k] = (short)f2bf(ea[8 + k]);
    }
    s16x8* op = reinterpret_cast<s16x8*>(&ea16[(size_t)p * DE]);
    op[0] = v0; op[1] = v1;
  }
}

// ---------------- weight preprocessing: transpose + bf16 hi/lo split ----
__global__ __launch_bounds__(256) void convertW_kernel(
    const float* __restrict__ W_ne, const float* __restrict__ W_pre,
    const float* __restrict__ W1_a, const float* __restrict__ W2_a,
    const float* __restrict__ W1_l, const float* __restrict__ W2_l,
    unsigned short* __restrict__ hi, unsigned short* __restrict__ lo)
{
  const int mat = blockIdx.y;
  const float* src;
  int K = 256;
  if (mat == 0)      { src = W_ne;  K = 64; }
  else if (mat == 1) { src = W_pre; }
  else if (mat == 2) { src = W1_a; }
  else if (mat == 3) { src = W2_a; }
  else if (mat < 8)  { src = W1_l + (size_t)(mat - 4) * 65536; }
  else               { src = W2_l + (size_t)(mat - 8) * 65536; }
  const size_t off = woff(mat);

  const int ntiles = (K >> 6) * 4;
  const int t = blockIdx.x;
  if (t >= ntiles) return;
  const int tk = t % (K >> 6);
  const int tn = t / (K >> 6);

  __shared__ float tile[64][65];
  const int tid = threadIdx.x;
  const int c = tid & 63;
  const int rg = tid >> 6;
  for (int i = 0; i < 16; ++i) {
    const int r = rg + i * 4;
    tile[r][c] = src[(size_t)(tk * 64 + r) * 256 + tn * 64 + c];
  }
  __syncthreads();
  const int k = tk * 64 + c;
  for (int i = 0; i < 16; ++i) {
    const int nn = rg + i * 4;
    const int n = tn * 64 + nn;
    const float x = tile[c][nn];
    const unsigned short hh = f2bf(x);
    hi[off + (size_t)n * K + k] = hh;
    lo[off + (size_t)n * K + k] = f2bf(x - bf2f(hh));
  }
}

// W_ee[16,256] -> Wt16[256][16] bf16 (transposed)
__global__ __launch_bounds__(256) void convertWee_kernel(
    const float* __restrict__ Wee, unsigned short* __restrict__ Wt16)
{
  const int n = threadIdx.x;  // 0..255
  #pragma unroll
  for (int k = 0; k < DE; ++k)
    Wt16[n * DE + k] = f2bf(Wee[k * DM + n]);
}

// ---------------- edge encoder: e16[p] = ea16[p] @ W_ee + b_ee ----------
// CSR-ordered in, CSR-ordered out. LDS-free MFMA; K=16 padded to 32.
__global__ __launch_bounds__(256) void eenc_kernel(
    const unsigned short* __restrict__ ea16, const unsigned short* __restrict__ Wt16,
    const float* __restrict__ bee, unsigned short* __restrict__ e16)
{
  const int tid = threadIdx.x;
  const int lane = tid & 63, wid = tid >> 6;
  const int l15 = lane & 15, l4 = lane >> 4;
  const int eBase = blockIdx.x * 128 + wid * 32;
  const int colBase = blockIdx.y * 128;
  const s16x8 zz = {0, 0, 0, 0, 0, 0, 0, 0};

  s16x8 ah[2];
  #pragma unroll
  for (int mi = 0; mi < 2; ++mi) {
    const int edge = eBase + mi * 16 + l15;
    ah[mi] = (l4 < 2)
        ? *reinterpret_cast<const s16x8*>(&ea16[(size_t)edge * DE + l4 * 8]) : zz;
  }
  s16x8 bh[8];
  #pragma unroll
  for (int ni = 0; ni < 8; ++ni) {
    const int col = colBase + ni * 16 + l15;
    bh[ni] = (l4 < 2)
        ? *reinterpret_cast<const s16x8*>(&Wt16[col * DE + l4 * 8]) : zz;
  }
  f32x4 acc[2][8];
  #pragma unroll
  for (int mi = 0; mi < 2; ++mi)
    #pragma unroll
    for (int ni = 0; ni < 8; ++ni)
      acc[mi][ni] = (f32x4){0.f, 0.f, 0.f, 0.f};
  #pragma unroll
  for (int mi = 0; mi < 2; ++mi)
    #pragma unroll
    for (int ni = 0; ni < 8; ++ni)
      acc[mi][ni] = __builtin_amdgcn_mfma_f32_16x16x32_bf16(ah[mi], bh[ni], acc[mi][ni], 0, 0, 0);

  #pragma unroll
  for (int ni = 0; ni < 8; ++ni) {
    const int col = colBase + ni * 16 + l15;
    const float bv = bee[col];
    #pragma unroll
    for (int mi = 0; mi < 2; ++mi) {
      #pragma unroll
      for (int r = 0; r < 4; ++r) {
        const int edge = eBase + mi * 16 + l4 * 4 + r;
        e16[(size_t)edge * DM + col] = f2bf(acc[mi][ni][r] + bv);
      }
    }
  }
}

// ---------------- MFMA matmul v2: BM=64 BN=128, split-bf16 3-term --------
template<bool RELU, bool RESID, bool HOUT>
__global__ __launch_bounds__(256) void mm_mfma(
    const float* __restrict__ A, const unsigned short* __restrict__ Bth,
    const unsigned short* __restrict__ Btl, const float* __restrict__ bias,
    float* __restrict__ C, unsigned short* __restrict__ H16, int M, int K)
{
  __shared__ unsigned short Ah[64 * 64], Al[64 * 64];
  __shared__ unsigned short Bh[128 * 64], Bl[128 * 64];
  const int tid = threadIdx.x;
  const int lane = tid & 63, wid = tid >> 6;
  const int wr = wid >> 1, wc = wid & 1;
  const int l15 = lane & 15, l4 = lane >> 4;
  const int rowBase = blockIdx.x * 64, colBase = blockIdx.y * 128;

  f32x4 acc[2][4];
  #pragma unroll
  for (int i = 0; i < 2; ++i)
    #pragma unroll
    for (int j = 0; j < 4; ++j) acc[i][j] = (f32x4){0.f, 0.f, 0.f, 0.f};

  const int nk = K >> 6;
  for (int ks = 0; ks < nk; ++ks) {
    // stage A: 64 rows x 64 k, fp32 -> bf16 hi/lo, chunk-XOR swizzle
    #pragma unroll
    for (int i = 0; i < 2; ++i) {
      const int u = tid + i * 256;
      const int row = u >> 3, kc = u & 7;
      const int grow = rowBase + row;
      float4 v0 = make_float4(0.f, 0.f, 0.f, 0.f), v1 = v0;
      if (grow < M) {
        const float* p = A + (size_t)grow * K + ks * 64 + kc * 8;
        v0 = *reinterpret_cast<const float4*>(p);
        v1 = *reinterpret_cast<const float4*>(p + 4);
      }
      const float xs[8] = {v0.x, v0.y, v0.z, v0.w, v1.x, v1.y, v1.z, v1.w};
      s16x8 hv, lv;
      #pragma unroll
      for (int j = 0; j < 8; ++j) {
        const unsigned short hh = f2bf(xs[j]);
        hv[j] = (short)hh;
        lv[j] = (short)f2bf(xs[j] - bf2f(hh));
      }
      const int chunk = row * 8 + (kc ^ (row & 7));
      ((s16x8*)Ah)[chunk] = hv;
      ((s16x8*)Al)[chunk] = lv;
    }
    // stage B: 128 n x 64 k
    #pragma unroll
    for (int i = 0; i < 4; ++i) {
      const int u = tid + i * 256;
      const int n = u >> 3, kc = u & 7;
      const size_t g = (size_t)(colBase + n) * K + ks * 64 + kc * 8;
      const int chunk = n * 8 + (kc ^ (n & 7));
      ((s16x8*)Bh)[chunk] = *reinterpret_cast<const s16x8*>(Bth + g);
      ((s16x8*)Bl)[chunk] = *reinterpret_cast<const s16x8*>(Btl + g);
    }
    __syncthreads();
    #pragma unroll
    for (int sub = 0; sub < 2; ++sub) {
      const int kc = sub * 4 + l4;
      s16x8 ah[2], al[2], bh[4], bl[4];
      #pragma unroll
      for (int mi = 0; mi < 2; ++mi) {
        const int r = wr * 32 + mi * 16 + l15;
        const int ch = r * 8 + (kc ^ (r & 7));
        ah[mi] = ((const s16x8*)Ah)[ch];
        al[mi] = ((const s16x8*)Al)[ch];
      }
      #pragma unroll
      for (int ni = 0; ni < 4; ++ni) {
        const int r = wc * 64 + ni * 16 + l15;
        const int ch = r * 8 + (kc ^ (r & 7));
        bh[ni] = ((const s16x8*)Bh)[ch];
        bl[ni] = ((const s16x8*)Bl)[ch];
      }
      #pragma unroll
      for (int mi = 0; mi < 2; ++mi)
        #pragma unroll
        for (int ni = 0; ni < 4; ++ni) {
          acc[mi][ni] = __builtin_amdgcn_mfma_f32_16x16x32_bf16(ah[mi], bh[ni], acc[mi][ni], 0, 0, 0);
          acc[mi][ni] = __builtin_amdgcn_mfma_f32_16x16x32_bf16(al[mi], bh[ni], acc[mi][ni], 0, 0, 0);
          acc[mi][ni] = __builtin_amdgcn_mfma_f32_16x16x32_bf16(ah[mi], bl[ni], acc[mi][ni], 0, 0, 0);
        }
    }
    __syncthreads();
  }

  #pragma unroll
  for (int ni = 0; ni < 4; ++ni) {
    const int gcol = colBase + wc * 64 + ni * 16 + l15;
    const float bv = bias[gcol];
    #pragma unroll
    for (int mi = 0; mi < 2; ++mi) {
      const int rbase = rowBase + wr * 32 + mi * 16 + l4 * 4;
      #pragma unroll
      for (int r = 0; r < 4; ++r) {
        const int grow = rbase + r;
        if (grow < M) {
          float v = acc[mi][ni][r] + bv;
          if (RESID) v += C[(size_t)grow * DM + gcol];
          if (RELU) v = fmaxf(v, 0.f);
          C[(size_t)grow * DM + gcol] = v;
          if (HOUT) H16[(size_t)grow * DM + gcol] = f2bf(v);
        }
      }
    }
  }
}

// ---------------- gather v4: precomputed e16, ~20 VALU/edge/lane --------
__global__ __launch_bounds__(256) void gather_e16_kernel(
    const float* __restrict__ h, const unsigned short* __restrict__ h16,
    const int* __restrict__ row_ptr, const int* __restrict__ esrc,
    const unsigned short* __restrict__ e16,
    const float* __restrict__ eps_ptr, int eps_idx,
    float* __restrict__ out, int n)
{
  const int tid = threadIdx.x;
  const int lane = tid & 63, wave = tid >> 6;
  const int c4 = lane * 4;
  const float ep1 = 1.0f + eps_ptr[eps_idx];
  const int stride = gridDim.x * 4;

  for (int i = blockIdx.x * 4 + wave; i < n; i += stride) {
    const int beg = row_ptr[i], end = row_ptr[i + 1];
    float a0 = 0.f, a1 = 0.f, a2 = 0.f, a3 = 0.f;
    int p = beg;
    for (; p + 2 <= end; p += 2) {
      const int s0 = esrc[p], s1 = esrc[p + 1];
      const ushort4 hv0 = *reinterpret_cast<const ushort4*>(&h16[(size_t)s0 * DM + c4]);
      const ushort4 ev0 = *reinterpret_cast<const ushort4*>(&e16[(size_t)p * DM + c4]);
      const ushort4 hv1 = *reinterpret_cast<const ushort4*>(&h16[(size_t)s1 * DM + c4]);
      const ushort4 ev1 = *reinterpret_cast<const ushort4*>(&e16[((size_t)p + 1) * DM + c4]);
      a0 += fmaxf(bf2f(hv0.x) + bf2f(ev0.x), 0.f);
      a1 += fmaxf(bf2f(hv0.y) + bf2f(ev0.y), 0.f);
      a2 += fmaxf(bf2f(hv0.z) + bf2f(ev0.z), 0.f);
      a3 += fmaxf(bf2f(hv0.w) + bf2f(ev0.w), 0.f);
      a0 += fmaxf(bf2f(hv1.x) + bf2f(ev1.x), 0.f);
      a1 += fmaxf(bf2f(hv1.y) + bf2f(ev1.y), 0.f);
      a2 += fmaxf(bf2f(hv1.z) + bf2f(ev1.z), 0.f);
      a3 += fmaxf(bf2f(hv1.w) + bf2f(ev1.w), 0.f);
    }
    if (p < end) {
      const int s0 = esrc[p];
      const ushort4 hv0 = *reinterpret_cast<const ushort4*>(&h16[(size_t)s0 * DM + c4]);
      const ushort4 ev0 = *reinterpret_cast<const ushort4*>(&e16[(size_t)p * DM + c4]);
      a0 += fmaxf(bf2f(hv0.x) + bf2f(ev0.x), 0.f);
      a1 += fmaxf(bf2f(hv0.y) + bf2f(ev0.y), 0.f);
      a2 += fmaxf(bf2f(hv0.z) + bf2f(ev0.z), 0.f);
      a3 += fmaxf(bf2f(hv0.w) + bf2f(ev0.w), 0.f);
    }
    const float4 hself = *reinterpret_cast<const float4*>(&h[(size_t)i * DM + c4]);
    float4 o;
    o.x = ep1 * hself.x + a0; o.y = ep1 * hself.y + a1;
    o.z = ep1 * hself.z + a2; o.w = ep1 * hself.w + a3;
    *reinterpret_cast<float4*>(&out[(size_t)i * DM + c4]) = o;
  }
}

// ---------------- gather fallback (round-5): recompute e per edge -------
__global__ __launch_bounds__(256) void gather_rc_kernel(
    const float* __restrict__ h, const unsigned short* __restrict__ h16,
    const int* __restrict__ row_ptr, const int* __restrict__ esrc,
    const unsigned short* __restrict__ ea16,
    const float* __restrict__ Wee, const float* __restrict__ bee,
    const float* __restrict__ eps_ptr, int eps_idx,
    float* __restrict__ out, int n)
{
  const int tid = threadIdx.x;
  const int lane = tid & 63, wave = tid >> 6;
  const int c4 = lane * 4;
  float4 w[16];
  #pragma unroll
  for (int k = 0; k < 16; ++k)
    w[k] = *reinterpret_cast<const float4*>(&Wee[k * DM + c4]);
  const float4 bv = *reinterpret_cast<const float4*>(&bee[c4]);
  const float ep1 = 1.0f + eps_ptr[eps_idx];
  const int stride = gridDim.x * 4;

  for (int i = blockIdx.x * 4 + wave; i < n; i += stride) {
    const int beg = row_ptr[i], end = row_ptr[i + 1];
    float a0 = 0.f, a1 = 0.f, a2 = 0.f, a3 = 0.f;
    for (int p = beg; p < end; ++p) {
      const int s = esrc[p];
      const ushort4 hv = *reinterpret_cast<const ushort4*>(&h16[(size_t)s * DM + c4]);
      const s16x8* eap = reinterpret_cast<const s16x8*>(&ea16[(size_t)p * DE]);
      const s16x8 ew0 = eap[0], ew1 = eap[1];
      float m0 = bf2f(hv.x) + bv.x, m1 = bf2f(hv.y) + bv.y;
      float m2 = bf2f(hv.z) + bv.z, m3 = bf2f(hv.w) + bv.w;
      float ea[16];
      #pragma unroll
      for (int k = 0; k < 8; ++k) {
        ea[k] = bf2f((unsigned short)ew0[k]);
        ea[8 + k] = bf2f((unsigned short)ew1[k]);
      }
      #pragma unroll
      for (int k = 0; k < 16; ++k) {
        m0 += ea[k] * w[k].x; m1 += ea[k] * w[k].y;
        m2 += ea[k] * w[k].z; m3 += ea[k] * w[k].w;
      }
      a0 += fmaxf(m0, 0.f); a1 += fmaxf(m1, 0.f);
      a2 += fmaxf(m2, 0.f); a3 += fmaxf(m3, 0.f);
    }
    const float4 hself = *reinterpret_cast<const float4*>(&h[(size_t)i * DM + c4]);
    float4 o;
    o.x = ep1 * hself.x + a0; o.y = ep1 * hself.y + a1;
    o.z = ep1 * hself.z + a2; o.w = ep1 * hself.w + a3;
    *reinterpret_cast<float4*>(&out[(size_t)i * DM + c4]) = o;
  }
}

// out[M,10] = h[M,256] @ W[256,10] + b
__global__ __launch_bounds__(256) void head_kernel(
    const float* __restrict__ h, const float* __restrict__ W,
    const float* __restrict__ b, float* __restrict__ out, int M)
{
  __shared__ float Ws[DM * DO];
  const int tid = threadIdx.x;
  for (int i = tid; i < DM * DO; i += 256) Ws[i] = W[i];
  __syncthreads();
  const int r = tid >> 4;
  const int c = tid & 15;
  const int row = blockIdx.x * 16 + r;
  if (row < M && c < DO) {
    const float* hp = &h[(size_t)row * DM];
    float acc = 0.f;
    #pragma unroll 8
    for (int k = 0; k < DM; ++k) acc += hp[k] * Ws[k * DO + c];
    out[(size_t)row * DO + c] = acc + b[c];
  }
}

}  // namespace

extern "C" void kernel_launch(void* const* d_in, const int* in_sizes, int n_in,
                              void* d_out, int out_size, void* d_ws, size_t ws_size,
                              hipStream_t stream) {
  const float* x     = (const float*)d_in[0];
  const float* eattr = (const float*)d_in[1];
  const int*   eidx  = (const int*)d_in[2];
  const float* W_ne  = (const float*)d_in[3];
  const float* b_ne  = (const float*)d_in[4];
  const float* W_ee  = (const float*)d_in[5];
  const float* b_ee  = (const float*)d_in[6];
  const float* W_pre = (const float*)d_in[7];
  const float* b_pre = (const float*)d_in[8];
  const float* eps_a = (const float*)d_in[9];
  const float* W1_a  = (const float*)d_in[10];
  const float* b1_a  = (const float*)d_in[11];
  const float* W2_a  = (const float*)d_in[12];
  const float* b2_a  = (const float*)d_in[13];
  const float* eps_l = (const float*)d_in[14];
  const float* W1_l  = (const float*)d_in[15];
  const float* b1_l  = (const float*)d_in[16];
  const float* W2_l  = (const float*)d_in[17];
  const float* b2_l  = (const float*)d_in[18];
  const float* W_h   = (const float*)d_in[19];
  const float* b_h   = (const float*)d_in[20];

  const int* src = eidx;
  const int* dst = eidx + NE;

  // workspace layout (e16 LAST so the fallback path needs none of it)
  char* wp = (char*)d_ws;
  float* h   = (float*)wp;                 wp += (size_t)NN * DM * 4;
  float* t   = (float*)wp;                 wp += (size_t)NN * DM * 4;
  float* agg = (float*)wp;                 wp += (size_t)NN * DM * 4;
  unsigned short* h16  = (unsigned short*)wp; wp += (size_t)NN * DM * 2;
  unsigned short* ea16 = (unsigned short*)wp; wp += (size_t)NE * DE * 2;
  unsigned short* wt_hi = (unsigned short*)wp; wp += WTOTAL * 2;
  unsigned short* wt_lo = (unsigned short*)wp; wp += WTOTAL * 2;
  unsigned short* wtee  = (unsigned short*)wp; wp += (size_t)DM * DE * 2;
  int* esrc    = (int*)wp;                 wp += (size_t)NE * 4;
  int* counts  = (int*)wp;                 wp += (size_t)NN * 4;
  int* row_ptr = (int*)wp;                 wp += (size_t)(NN + 1) * 4;
  int* cursor  = (int*)wp;                 wp += (size_t)NN * 4;
  // align to 16 for e16
  wp = (char*)(((uintptr_t)wp + 15) & ~(uintptr_t)15);
  unsigned short* e16 = (unsigned short*)wp;
  const size_t need_e16 = (size_t)(wp - (char*)d_ws) + (size_t)NE * DM * 2;
  const bool use_e16 = ws_size >= need_e16;

  // ---- CSR build ----
  hipMemsetAsync(counts, 0, NN * sizeof(int), stream);
  hist_kernel<<<(NE + 255) / 256, 256, 0, stream>>>(dst, counts, NE);
  scan_kernel<<<1, 1024, 0, stream>>>(counts, row_ptr, cursor, NN);
  scatter_kernel<<<(NE + 255) / 256, 256, 0, stream>>>(
      src, dst, eattr, cursor, esrc, ea16, NE);

  // ---- weight preprocessing ----
  convertW_kernel<<<dim3(16, 12), 256, 0, stream>>>(
      W_ne, W_pre, W1_a, W2_a, W1_l, W2_l, wt_hi, wt_lo);
  convertWee_kernel<<<1, 256, 0, stream>>>(W_ee, wtee);

  // ---- edge encoder (layer-invariant), once ----
  if (use_e16)
    eenc_kernel<<<dim3(NE / 128, 2), 256, 0, stream>>>(ea16, wtee, b_ee, e16);

  const dim3 mmgrid((NN + 63) / 64, 2);

  // encoder: t = x @ W_ne + b_ne   (K=64)
  mm_mfma<false, false, false><<<mmgrid, 256, 0, stream>>>(
      x, wt_hi + woff(0), wt_lo + woff(0), b_ne, t, nullptr, NN, DI);
  // pre-MP: h = relu(t @ W_pre + b_pre)  (+ bf16 copy)
  mm_mfma<true, false, true><<<mmgrid, 256, 0, stream>>>(
      t, wt_hi + woff(1), wt_lo + woff(1), b_pre, h, h16, NN, DM);

  for (int layer = 0; layer < 5; ++layer) {
    const float* eps; int ei; const float *b1, *b2; size_t o1, o2; bool resid;
    if (layer == 0) {
      eps = eps_a; ei = 0; b1 = b1_a; b2 = b2_a;
      o1 = woff(2); o2 = woff(3); resid = false;
    } else {
      const int i = layer - 1;
      eps = eps_l; ei = i;
      b1 = b1_l + (size_t)i * DM; b2 = b2_l + (size_t)i * DM;
      o1 = woff(4 + i); o2 = woff(8 + i); resid = true;
    }
    if (use_e16)
      gather_e16_kernel<<<2500, 256, 0, stream>>>(
          h, h16, row_ptr, esrc, e16, eps, ei, agg, NN);
    else
      gather_rc_kernel<<<1280, 256, 0, stream>>>(
          h, h16, row_ptr, esrc, ea16, W_ee, b_ee, eps, ei, agg, NN);
    mm_mfma<true, false, false><<<mmgrid, 256, 0, stream>>>(
        agg, wt_hi + o1, wt_lo + o1, b1, t, nullptr, NN, DM);
    if (resid)
      mm_mfma<false, true, true><<<mmgrid, 256, 0, stream>>>(
          t, wt_hi + o2, wt_lo + o2, b2, h, h16, NN, DM);
    else
      mm_mfma<false, false, true><<<mmgrid, 256, 0, stream>>>(
          t, wt_hi + o2, wt_lo + o2, b2, h, h16, NN, DM);
  }

  head_kernel<<<(NN + 15) / 16, 256, 0, stream>>>(h, W_h, b_h, (float*)d_out, NN);
}

// Round 7
// 635.299 us; speedup vs baseline: 9.4113x; 1.1926x over previous
//
#include <hip/hip_runtime.h>
#include <hip/hip_bf16.h>

namespace {

constexpr int NN = 20000;   // nodes
constexpr int NE = 320000;  // edges
constexpr int DI = 64;      // input node dim
constexpr int DE = 16;      // edge attr dim
constexpr int DM = 256;     // hidden dim
constexpr int DO = 10;      // out dim

// weight-plane offsets: mat 0 = W_ne (64*256), mats 1..11 = 256*256 each
__host__ __device__ constexpr size_t woff(int m) {
  return m == 0 ? 0 : (size_t)16384 + (size_t)(m - 1) * 65536;
}
constexpr size_t WTOTAL = 16384 + 11 * 65536;

typedef __attribute__((ext_vector_type(8))) short s16x8;
typedef __attribute__((ext_vector_type(4))) float f32x4;

__device__ inline unsigned short f2bf(float x) {
  union { float f; unsigned u; } c; c.f = x;
  unsigned r = (c.u + 0x7FFFu + ((c.u >> 16) & 1u)) >> 16;
  return (unsigned short)r;
}
__device__ inline float bf2f(unsigned short h) {
  union { unsigned u; float f; } c; c.u = ((unsigned)h) << 16;
  return c.f;
}

// ---------------- CSR build (counting sort by dst) ----------------

__global__ __launch_bounds__(256) void hist_kernel(
    const int* __restrict__ dst, int* __restrict__ counts, int E)
{
  const int j = blockIdx.x * 256 + threadIdx.x;
  if (j < E) atomicAdd(&counts[dst[j]], 1);
}

__global__ __launch_bounds__(1024) void scan_kernel(
    const int* __restrict__ counts, int* __restrict__ row_ptr,
    int* __restrict__ cursor, int n)
{
  __shared__ int partial[1024];
  const int t = threadIdx.x;
  const int chunk = (n + 1023) / 1024;
  const int beg = t * chunk;
  const int end = min(beg + chunk, n);
  int s = 0;
  for (int i = beg; i < end; ++i) s += counts[i];
  partial[t] = s;
  __syncthreads();
  for (int off = 1; off < 1024; off <<= 1) {
    const int v = (t >= off) ? partial[t - off] : 0;
    __syncthreads();
    partial[t] += v;
    __syncthreads();
  }
  int base = (t == 0) ? 0 : partial[t - 1];
  for (int i = beg; i < end; ++i) {
    const int c = counts[i];
    row_ptr[i] = base;
    cursor[i] = base;
    base += c;
  }
  if (t == 1023) row_ptr[n] = partial[1023];
}

// CSR scatter: edge attrs re-ordered into CSR order as bf16.
__global__ __launch_bounds__(256) void scatter_kernel(
    const int* __restrict__ src, const int* __restrict__ dst,
    const float* __restrict__ eattr, int* __restrict__ cursor,
    int* __restrict__ esrc, unsigned short* __restrict__ ea16, int E)
{
  const int j = blockIdx.x * 256 + threadIdx.x;
  if (j < E) {
    const int p = atomicAdd(&cursor[dst[j]], 1);
    esrc[p] = src[j];
    const float4* ep = reinterpret_cast<const float4*>(&eattr[(size_t)j * DE]);
    const float4 e0 = ep[0], e1 = ep[1], e2 = ep[2], e3 = ep[3];
    const float ea[16] = {e0.x, e0.y, e0.z, e0.w, e1.x, e1.y, e1.z, e1.w,
                          e2.x, e2.y, e2.z, e2.w, e3.x, e3.y, e3.z, e3.w};
    s16x8 v0, v1;
    #pragma unroll
    for (int k = 0; k < 8; ++k) {
      v0[k] = (short)f2bf(ea[k]);
      v1[k] = (short)f2bf(ea[8 + k]);
    }
    s16x8* op = reinterpret_cast<s16x8*>(&ea16[(size_t)p * DE]);
    op[0] = v0; op[1] = v1;
  }
}

// ---------------- weight preprocessing: transpose + bf16 hi/lo split ----
__global__ __launch_bounds__(256) void convertW_kernel(
    const float* __restrict__ W_ne, const float* __restrict__ W_pre,
    const float* __restrict__ W1_a, const float* __restrict__ W2_a,
    const float* __restrict__ W1_l, const float* __restrict__ W2_l,
    unsigned short* __restrict__ hi, unsigned short* __restrict__ lo)
{
  const int mat = blockIdx.y;
  const float* src;
  int K = 256;
  if (mat == 0)      { src = W_ne;  K = 64; }
  else if (mat == 1) { src = W_pre; }
  else if (mat == 2) { src = W1_a; }
  else if (mat == 3) { src = W2_a; }
  else if (mat < 8)  { src = W1_l + (size_t)(mat - 4) * 65536; }
  else               { src = W2_l + (size_t)(mat - 8) * 65536; }
  const size_t off = woff(mat);

  const int ntiles = (K >> 6) * 4;
  const int t = blockIdx.x;
  if (t >= ntiles) return;
  const int tk = t % (K >> 6);
  const int tn = t / (K >> 6);

  __shared__ float tile[64][65];
  const int tid = threadIdx.x;
  const int c = tid & 63;
  const int rg = tid >> 6;
  for (int i = 0; i < 16; ++i) {
    const int r = rg + i * 4;
    tile[r][c] = src[(size_t)(tk * 64 + r) * 256 + tn * 64 + c];
  }
  __syncthreads();
  const int k = tk * 64 + c;
  for (int i = 0; i < 16; ++i) {
    const int nn = rg + i * 4;
    const int n = tn * 64 + nn;
    const float x = tile[c][nn];
    const unsigned short hh = f2bf(x);
    hi[off + (size_t)n * K + k] = hh;
    lo[off + (size_t)n * K + k] = f2bf(x - bf2f(hh));
  }
}

// W_ee[16,256] -> Wt16[256][16] bf16 (transposed)
__global__ __launch_bounds__(256) void convertWee_kernel(
    const float* __restrict__ Wee, unsigned short* __restrict__ Wt16)
{
  const int n = threadIdx.x;  // 0..255
  #pragma unroll
  for (int k = 0; k < DE; ++k)
    Wt16[n * DE + k] = f2bf(Wee[k * DM + n]);
}

// ---------------- edge encoder: e16[p] = ea16[p] @ W_ee + b_ee ----------
// LDS-staged coalesced output: 256 B contiguous per edge per block.
__global__ __launch_bounds__(256) void eenc_kernel(
    const unsigned short* __restrict__ ea16, const unsigned short* __restrict__ Wt16,
    const float* __restrict__ bee, unsigned short* __restrict__ e16)
{
  __shared__ unsigned short stage[128][136];  // +8 pad, rows 16B-aligned
  const int tid = threadIdx.x;
  const int lane = tid & 63, wid = tid >> 6;
  const int l15 = lane & 15, l4 = lane >> 4;
  const int eBase0 = blockIdx.x * 128;
  const int eBase = eBase0 + wid * 32;
  const int colBase = blockIdx.y * 128;
  const s16x8 zz = {0, 0, 0, 0, 0, 0, 0, 0};

  s16x8 ah[2];
  #pragma unroll
  for (int mi = 0; mi < 2; ++mi) {
    const int edge = eBase + mi * 16 + l15;
    ah[mi] = (l4 < 2)
        ? *reinterpret_cast<const s16x8*>(&ea16[(size_t)edge * DE + l4 * 8]) : zz;
  }
  s16x8 bh[8];
  #pragma unroll
  for (int ni = 0; ni < 8; ++ni) {
    const int col = colBase + ni * 16 + l15;
    bh[ni] = (l4 < 2)
        ? *reinterpret_cast<const s16x8*>(&Wt16[col * DE + l4 * 8]) : zz;
  }
  f32x4 acc[2][8];
  #pragma unroll
  for (int mi = 0; mi < 2; ++mi)
    #pragma unroll
    for (int ni = 0; ni < 8; ++ni)
      acc[mi][ni] = (f32x4){0.f, 0.f, 0.f, 0.f};
  #pragma unroll
  for (int mi = 0; mi < 2; ++mi)
    #pragma unroll
    for (int ni = 0; ni < 8; ++ni)
      acc[mi][ni] = __builtin_amdgcn_mfma_f32_16x16x32_bf16(ah[mi], bh[ni], acc[mi][ni], 0, 0, 0);

  #pragma unroll
  for (int ni = 0; ni < 8; ++ni) {
    const int col = ni * 16 + l15;
    const float bv = bee[colBase + col];
    #pragma unroll
    for (int mi = 0; mi < 2; ++mi) {
      #pragma unroll
      for (int r = 0; r < 4; ++r) {
        const int erow = wid * 32 + mi * 16 + l4 * 4 + r;
        stage[erow][col] = f2bf(acc[mi][ni][r] + bv);
      }
    }
  }
  __syncthreads();
  // coalesced out: 16 threads x 16 B = 256 B contiguous per edge
  #pragma unroll
  for (int it = 0; it < 8; ++it) {
    const int idx = tid + it * 256;
    const int e = idx >> 4, cc = idx & 15;
    const s16x8 v = *reinterpret_cast<const s16x8*>(&stage[e][cc * 8]);
    *reinterpret_cast<s16x8*>(&e16[(size_t)(eBase0 + e) * DM + colBase + cc * 8]) = v;
  }
}

// ---------------- MFMA matmul: BM=64 BN=128 ----------
// ABF16: A is bf16 [M,K] (2-term MFMA). else fp32 A, split hi/lo (3-term).
// F32OUT: write C fp32 (+RESID) and O16 bf16. else write O16 only.
template<bool RELU, bool RESID, bool ABF16, bool F32OUT>
__global__ __launch_bounds__(256) void mm_mfma(
    const float* __restrict__ Af, const unsigned short* __restrict__ Ab,
    const unsigned short* __restrict__ Bth, const unsigned short* __restrict__ Btl,
    const float* __restrict__ bias,
    float* __restrict__ C, unsigned short* __restrict__ O16, int M, int K)
{
  __shared__ unsigned short Ah[64 * 64];
  __shared__ unsigned short Al[ABF16 ? 8 : 64 * 64];
  __shared__ unsigned short Bh[128 * 64], Bl[128 * 64];
  const int tid = threadIdx.x;
  const int lane = tid & 63, wid = tid >> 6;
  const int wr = wid >> 1, wc = wid & 1;
  const int l15 = lane & 15, l4 = lane >> 4;
  const int rowBase = blockIdx.x * 64, colBase = blockIdx.y * 128;

  f32x4 acc[2][4];
  #pragma unroll
  for (int i = 0; i < 2; ++i)
    #pragma unroll
    for (int j = 0; j < 4; ++j) acc[i][j] = (f32x4){0.f, 0.f, 0.f, 0.f};

  const int nk = K >> 6;
  for (int ks = 0; ks < nk; ++ks) {
    // stage A
    #pragma unroll
    for (int i = 0; i < 2; ++i) {
      const int u = tid + i * 256;
      const int row = u >> 3, kc = u & 7;
      const int grow = rowBase + row;
      const int chunk = row * 8 + (kc ^ (row & 7));
      if (ABF16) {
        s16x8 v = {0, 0, 0, 0, 0, 0, 0, 0};
        if (grow < M)
          v = *reinterpret_cast<const s16x8*>(&Ab[(size_t)grow * K + ks * 64 + kc * 8]);
        ((s16x8*)Ah)[chunk] = v;
      } else {
        float4 v0 = make_float4(0.f, 0.f, 0.f, 0.f), v1 = v0;
        if (grow < M) {
          const float* p = Af + (size_t)grow * K + ks * 64 + kc * 8;
          v0 = *reinterpret_cast<const float4*>(p);
          v1 = *reinterpret_cast<const float4*>(p + 4);
        }
        const float xs[8] = {v0.x, v0.y, v0.z, v0.w, v1.x, v1.y, v1.z, v1.w};
        s16x8 hv, lv;
        #pragma unroll
        for (int j = 0; j < 8; ++j) {
          const unsigned short hh = f2bf(xs[j]);
          hv[j] = (short)hh;
          lv[j] = (short)f2bf(xs[j] - bf2f(hh));
        }
        ((s16x8*)Ah)[chunk] = hv;
        ((s16x8*)Al)[chunk] = lv;
      }
    }
    // stage B: 128 n x 64 k
    #pragma unroll
    for (int i = 0; i < 4; ++i) {
      const int u = tid + i * 256;
      const int n = u >> 3, kc = u & 7;
      const size_t g = (size_t)(colBase + n) * K + ks * 64 + kc * 8;
      const int chunk = n * 8 + (kc ^ (n & 7));
      ((s16x8*)Bh)[chunk] = *reinterpret_cast<const s16x8*>(Bth + g);
      ((s16x8*)Bl)[chunk] = *reinterpret_cast<const s16x8*>(Btl + g);
    }
    __syncthreads();
    #pragma unroll
    for (int sub = 0; sub < 2; ++sub) {
      const int kc = sub * 4 + l4;
      s16x8 ah[2], al[2], bh[4], bl[4];
      #pragma unroll
      for (int mi = 0; mi < 2; ++mi) {
        const int r = wr * 32 + mi * 16 + l15;
        const int ch = r * 8 + (kc ^ (r & 7));
        ah[mi] = ((const s16x8*)Ah)[ch];
        if (!ABF16) al[mi] = ((const s16x8*)Al)[ch];
      }
      #pragma unroll
      for (int ni = 0; ni < 4; ++ni) {
        const int r = wc * 64 + ni * 16 + l15;
        const int ch = r * 8 + (kc ^ (r & 7));
        bh[ni] = ((const s16x8*)Bh)[ch];
        bl[ni] = ((const s16x8*)Bl)[ch];
      }
      #pragma unroll
      for (int mi = 0; mi < 2; ++mi)
        #pragma unroll
        for (int ni = 0; ni < 4; ++ni) {
          acc[mi][ni] = __builtin_amdgcn_mfma_f32_16x16x32_bf16(ah[mi], bh[ni], acc[mi][ni], 0, 0, 0);
          acc[mi][ni] = __builtin_amdgcn_mfma_f32_16x16x32_bf16(ah[mi], bl[ni], acc[mi][ni], 0, 0, 0);
          if (!ABF16)
            acc[mi][ni] = __builtin_amdgcn_mfma_f32_16x16x32_bf16(al[mi], bh[ni], acc[mi][ni], 0, 0, 0);
        }
    }
    __syncthreads();
  }

  #pragma unroll
  for (int ni = 0; ni < 4; ++ni) {
    const int gcol = colBase + wc * 64 + ni * 16 + l15;
    const float bv = bias[gcol];
    #pragma unroll
    for (int mi = 0; mi < 2; ++mi) {
      const int rbase = rowBase + wr * 32 + mi * 16 + l4 * 4;
      #pragma unroll
      for (int r = 0; r < 4; ++r) {
        const int grow = rbase + r;
        if (grow < M) {
          float v = acc[mi][ni][r] + bv;
          if (RESID) v += C[(size_t)grow * DM + gcol];
          if (RELU) v = fmaxf(v, 0.f);
          if (F32OUT) C[(size_t)grow * DM + gcol] = v;
          O16[(size_t)grow * DM + gcol] = f2bf(v);
        }
      }
    }
  }
}

// ---------------- gather: precomputed e16, bf16 out --------
__global__ __launch_bounds__(256) void gather_e16_kernel(
    const float* __restrict__ h, const unsigned short* __restrict__ h16,
    const int* __restrict__ row_ptr, const int* __restrict__ esrc,
    const unsigned short* __restrict__ e16,
    const float* __restrict__ eps_ptr, int eps_idx,
    unsigned short* __restrict__ out16, int n)
{
  const int tid = threadIdx.x;
  const int lane = tid & 63, wave = tid >> 6;
  const int c4 = lane * 4;
  const float ep1 = 1.0f + eps_ptr[eps_idx];
  const int stride = gridDim.x * 4;

  for (int i = blockIdx.x * 4 + wave; i < n; i += stride) {
    const int beg = row_ptr[i], end = row_ptr[i + 1];
    float a0 = 0.f, a1 = 0.f, a2 = 0.f, a3 = 0.f;
    int p = beg;
    for (; p + 2 <= end; p += 2) {
      const int s0 = esrc[p], s1 = esrc[p + 1];
      const ushort4 hv0 = *reinterpret_cast<const ushort4*>(&h16[(size_t)s0 * DM + c4]);
      const ushort4 ev0 = *reinterpret_cast<const ushort4*>(&e16[(size_t)p * DM + c4]);
      const ushort4 hv1 = *reinterpret_cast<const ushort4*>(&h16[(size_t)s1 * DM + c4]);
      const ushort4 ev1 = *reinterpret_cast<const ushort4*>(&e16[((size_t)p + 1) * DM + c4]);
      a0 += fmaxf(bf2f(hv0.x) + bf2f(ev0.x), 0.f);
      a1 += fmaxf(bf2f(hv0.y) + bf2f(ev0.y), 0.f);
      a2 += fmaxf(bf2f(hv0.z) + bf2f(ev0.z), 0.f);
      a3 += fmaxf(bf2f(hv0.w) + bf2f(ev0.w), 0.f);
      a0 += fmaxf(bf2f(hv1.x) + bf2f(ev1.x), 0.f);
      a1 += fmaxf(bf2f(hv1.y) + bf2f(ev1.y), 0.f);
      a2 += fmaxf(bf2f(hv1.z) + bf2f(ev1.z), 0.f);
      a3 += fmaxf(bf2f(hv1.w) + bf2f(ev1.w), 0.f);
    }
    if (p < end) {
      const int s0 = esrc[p];
      const ushort4 hv0 = *reinterpret_cast<const ushort4*>(&h16[(size_t)s0 * DM + c4]);
      const ushort4 ev0 = *reinterpret_cast<const ushort4*>(&e16[(size_t)p * DM + c4]);
      a0 += fmaxf(bf2f(hv0.x) + bf2f(ev0.x), 0.f);
      a1 += fmaxf(bf2f(hv0.y) + bf2f(ev0.y), 0.f);
      a2 += fmaxf(bf2f(hv0.z) + bf2f(ev0.z), 0.f);
      a3 += fmaxf(bf2f(hv0.w) + bf2f(ev0.w), 0.f);
    }
    const float4 hself = *reinterpret_cast<const float4*>(&h[(size_t)i * DM + c4]);
    ushort4 o;
    o.x = f2bf(ep1 * hself.x + a0); o.y = f2bf(ep1 * hself.y + a1);
    o.z = f2bf(ep1 * hself.z + a2); o.w = f2bf(ep1 * hself.w + a3);
    *reinterpret_cast<ushort4*>(&out16[(size_t)i * DM + c4]) = o;
  }
}

// ---------------- gather fallback: recompute e per edge -------
__global__ __launch_bounds__(256) void gather_rc_kernel(
    const float* __restrict__ h, const unsigned short* __restrict__ h16,
    const int* __restrict__ row_ptr, const int* __restrict__ esrc,
    const unsigned short* __restrict__ ea16,
    const float* __restrict__ Wee, const float* __restrict__ bee,
    const float* __restrict__ eps_ptr, int eps_idx,
    unsigned short* __restrict__ out16, int n)
{
  const int tid = threadIdx.x;
  const int lane = tid & 63, wave = tid >> 6;
  const int c4 = lane * 4;
  float4 w[16];
  #pragma unroll
  for (int k = 0; k < 16; ++k)
    w[k] = *reinterpret_cast<const float4*>(&Wee[k * DM + c4]);
  const float4 bv = *reinterpret_cast<const float4*>(&bee[c4]);
  const float ep1 = 1.0f + eps_ptr[eps_idx];
  const int stride = gridDim.x * 4;

  for (int i = blockIdx.x * 4 + wave; i < n; i += stride) {
    const int beg = row_ptr[i], end = row_ptr[i + 1];
    float a0 = 0.f, a1 = 0.f, a2 = 0.f, a3 = 0.f;
    for (int p = beg; p < end; ++p) {
      const int s = esrc[p];
      const ushort4 hv = *reinterpret_cast<const ushort4*>(&h16[(size_t)s * DM + c4]);
      const s16x8* eap = reinterpret_cast<const s16x8*>(&ea16[(size_t)p * DE]);
      const s16x8 ew0 = eap[0], ew1 = eap[1];
      float m0 = bf2f(hv.x) + bv.x, m1 = bf2f(hv.y) + bv.y;
      float m2 = bf2f(hv.z) + bv.z, m3 = bf2f(hv.w) + bv.w;
      float ea[16];
      #pragma unroll
      for (int k = 0; k < 8; ++k) {
        ea[k] = bf2f((unsigned short)ew0[k]);
        ea[8 + k] = bf2f((unsigned short)ew1[k]);
      }
      #pragma unroll
      for (int k = 0; k < 16; ++k) {
        m0 += ea[k] * w[k].x; m1 += ea[k] * w[k].y;
        m2 += ea[k] * w[k].z; m3 += ea[k] * w[k].w;
      }
      a0 += fmaxf(m0, 0.f); a1 += fmaxf(m1, 0.f);
      a2 += fmaxf(m2, 0.f); a3 += fmaxf(m3, 0.f);
    }
    const float4 hself = *reinterpret_cast<const float4*>(&h[(size_t)i * DM + c4]);
    ushort4 o;
    o.x = f2bf(ep1 * hself.x + a0); o.y = f2bf(ep1 * hself.y + a1);
    o.z = f2bf(ep1 * hself.z + a2); o.w = f2bf(ep1 * hself.w + a3);
    *reinterpret_cast<ushort4*>(&out16[(size_t)i * DM + c4]) = o;
  }
}

// out[M,10] = h[M,256] @ W[256,10] + b
__global__ __launch_bounds__(256) void head_kernel(
    const float* __restrict__ h, const float* __restrict__ W,
    const float* __restrict__ b, float* __restrict__ out, int M)
{
  __shared__ float Ws[DM * DO];
  const int tid = threadIdx.x;
  for (int i = tid; i < DM * DO; i += 256) Ws[i] = W[i];
  __syncthreads();
  const int r = tid >> 4;
  const int c = tid & 15;
  const int row = blockIdx.x * 16 + r;
  if (row < M && c < DO) {
    const float* hp = &h[(size_t)row * DM];
    float acc = 0.f;
    #pragma unroll 8
    for (int k = 0; k < DM; ++k) acc += hp[k] * Ws[k * DO + c];
    out[(size_t)row * DO + c] = acc + b[c];
  }
}

}  // namespace

extern "C" void kernel_launch(void* const* d_in, const int* in_sizes, int n_in,
                              void* d_out, int out_size, void* d_ws, size_t ws_size,
                              hipStream_t stream) {
  const float* x     = (const float*)d_in[0];
  const float* eattr = (const float*)d_in[1];
  const int*   eidx  = (const int*)d_in[2];
  const float* W_ne  = (const float*)d_in[3];
  const float* b_ne  = (const float*)d_in[4];
  const float* W_ee  = (const float*)d_in[5];
  const float* b_ee  = (const float*)d_in[6];
  const float* W_pre = (const float*)d_in[7];
  const float* b_pre = (const float*)d_in[8];
  const float* eps_a = (const float*)d_in[9];
  const float* W1_a  = (const float*)d_in[10];
  const float* b1_a  = (const float*)d_in[11];
  const float* W2_a  = (const float*)d_in[12];
  const float* b2_a  = (const float*)d_in[13];
  const float* eps_l = (const float*)d_in[14];
  const float* W1_l  = (const float*)d_in[15];
  const float* b1_l  = (const float*)d_in[16];
  const float* W2_l  = (const float*)d_in[17];
  const float* b2_l  = (const float*)d_in[18];
  const float* W_h   = (const float*)d_in[19];
  const float* b_h   = (const float*)d_in[20];

  const int* src = eidx;
  const int* dst = eidx + NE;

  // workspace layout (e16 LAST; fallback path needs none of it)
  char* wp = (char*)d_ws;
  float* h    = (float*)wp;                    wp += (size_t)NN * DM * 4;
  unsigned short* h16   = (unsigned short*)wp; wp += (size_t)NN * DM * 2;
  unsigned short* t16   = (unsigned short*)wp; wp += (size_t)NN * DM * 2;
  unsigned short* agg16 = (unsigned short*)wp; wp += (size_t)NN * DM * 2;
  unsigned short* ea16  = (unsigned short*)wp; wp += (size_t)NE * DE * 2;
  unsigned short* wt_hi = (unsigned short*)wp; wp += WTOTAL * 2;
  unsigned short* wt_lo = (unsigned short*)wp; wp += WTOTAL * 2;
  unsigned short* wtee  = (unsigned short*)wp; wp += (size_t)DM * DE * 2;
  int* esrc    = (int*)wp;                     wp += (size_t)NE * 4;
  int* counts  = (int*)wp;                     wp += (size_t)NN * 4;
  int* row_ptr = (int*)wp;                     wp += (size_t)(NN + 1) * 4;
  int* cursor  = (int*)wp;                     wp += (size_t)NN * 4;
  wp = (char*)(((uintptr_t)wp + 15) & ~(uintptr_t)15);
  unsigned short* e16 = (unsigned short*)wp;
  const size_t need_e16 = (size_t)(wp - (char*)d_ws) + (size_t)NE * DM * 2;
  const bool use_e16 = ws_size >= need_e16;

  // ---- CSR build ----
  hipMemsetAsync(counts, 0, NN * sizeof(int), stream);
  hist_kernel<<<(NE + 255) / 256, 256, 0, stream>>>(dst, counts, NE);
  scan_kernel<<<1, 1024, 0, stream>>>(counts, row_ptr, cursor, NN);
  scatter_kernel<<<(NE + 255) / 256, 256, 0, stream>>>(
      src, dst, eattr, cursor, esrc, ea16, NE);

  // ---- weight preprocessing ----
  convertW_kernel<<<dim3(16, 12), 256, 0, stream>>>(
      W_ne, W_pre, W1_a, W2_a, W1_l, W2_l, wt_hi, wt_lo);
  convertWee_kernel<<<1, 256, 0, stream>>>(W_ee, wtee);

  // ---- edge encoder (layer-invariant), once ----
  if (use_e16)
    eenc_kernel<<<dim3(NE / 128, 2), 256, 0, stream>>>(ea16, wtee, b_ee, e16);

  const dim3 mmgrid((NN + 63) / 64, 2);

  // encoder: t16 = x @ W_ne + b_ne   (K=64, fp32 A, bf16 out)
  mm_mfma<false, false, false, false><<<mmgrid, 256, 0, stream>>>(
      x, nullptr, wt_hi + woff(0), wt_lo + woff(0), b_ne, nullptr, t16, NN, DI);
  // pre-MP: h = relu(t16 @ W_pre + b_pre)  (fp32 + bf16 out)
  mm_mfma<true, false, true, true><<<mmgrid, 256, 0, stream>>>(
      nullptr, t16, wt_hi + woff(1), wt_lo + woff(1), b_pre, h, h16, NN, DM);

  for (int layer = 0; layer < 5; ++layer) {
    const float* eps; int ei; const float *b1, *b2; size_t o1, o2; bool resid;
    if (layer == 0) {
      eps = eps_a; ei = 0; b1 = b1_a; b2 = b2_a;
      o1 = woff(2); o2 = woff(3); resid = false;
    } else {
      const int i = layer - 1;
      eps = eps_l; ei = i;
      b1 = b1_l + (size_t)i * DM; b2 = b2_l + (size_t)i * DM;
      o1 = woff(4 + i); o2 = woff(8 + i); resid = true;
    }
    if (use_e16)
      gather_e16_kernel<<<2500, 256, 0, stream>>>(
          h, h16, row_ptr, esrc, e16, eps, ei, agg16, NN);
    else
      gather_rc_kernel<<<1280, 256, 0, stream>>>(
          h, h16, row_ptr, esrc, ea16, W_ee, b_ee, eps, ei, agg16, NN);
    // t16 = relu(agg16 @ W1 + b1)
    mm_mfma<true, false, true, false><<<mmgrid, 256, 0, stream>>>(
        nullptr, agg16, wt_hi + o1, wt_lo + o1, b1, nullptr, t16, NN, DM);
    // h = [h +] t16 @ W2 + b2   (+ h16)
    if (resid)
      mm_mfma<false, true, true, true><<<mmgrid, 256, 0, stream>>>(
          nullptr, t16, wt_hi + o2, wt_lo + o2, b2, h, h16, NN, DM);
    else
      mm_mfma<false, false, true, true><<<mmgrid, 256, 0, stream>>>(
          nullptr, t16, wt_hi + o2, wt_lo + o2, b2, h, h16, NN, DM);
  }

  head_kernel<<<(NN + 15) / 16, 256, 0, stream>>>(h, W_h, b_h, (float*)d_out, NN);
}

// Round 8
// 564.765 us; speedup vs baseline: 10.5867x; 1.1249x over previous
//
#include <hip/hip_runtime.h>
#include <hip/hip_bf16.h>

namespace {

constexpr int NN = 20000;   // nodes
constexpr int NE = 320000;  // edges
constexpr int DI = 64;      // input node dim
constexpr int DE = 16;      // edge attr dim
constexpr int DM = 256;     // hidden dim
constexpr int DO = 10;      // out dim

// weight-plane offsets: mat 0 = W_ne (64*256), mats 1..11 = 256*256 each
__host__ __device__ constexpr size_t woff(int m) {
  return m == 0 ? 0 : (size_t)16384 + (size_t)(m - 1) * 65536;
}
constexpr size_t WTOTAL = 16384 + 11 * 65536;

typedef __attribute__((ext_vector_type(8))) short s16x8;
typedef __attribute__((ext_vector_type(4))) float f32x4;

__device__ inline unsigned short f2bf(float x) {
  union { float f; unsigned u; } c; c.f = x;
  unsigned r = (c.u + 0x7FFFu + ((c.u >> 16) & 1u)) >> 16;
  return (unsigned short)r;
}
__device__ inline float bf2f(unsigned short h) {
  union { unsigned u; float f; } c; c.u = ((unsigned)h) << 16;
  return c.f;
}

// ---------------- CSR build (counting sort by dst) ----------------

__global__ __launch_bounds__(256) void hist_kernel(
    const int* __restrict__ dst, int* __restrict__ counts, int E)
{
  const int j = blockIdx.x * 256 + threadIdx.x;
  if (j < E) atomicAdd(&counts[dst[j]], 1);
}

__global__ __launch_bounds__(1024) void scan_kernel(
    const int* __restrict__ counts, int* __restrict__ row_ptr,
    int* __restrict__ cursor, int n)
{
  __shared__ int partial[1024];
  const int t = threadIdx.x;
  const int chunk = (n + 1023) / 1024;
  const int beg = t * chunk;
  const int end = min(beg + chunk, n);
  int s = 0;
  for (int i = beg; i < end; ++i) s += counts[i];
  partial[t] = s;
  __syncthreads();
  for (int off = 1; off < 1024; off <<= 1) {
    const int v = (t >= off) ? partial[t - off] : 0;
    __syncthreads();
    partial[t] += v;
    __syncthreads();
  }
  int base = (t == 0) ? 0 : partial[t - 1];
  for (int i = beg; i < end; ++i) {
    const int c = counts[i];
    row_ptr[i] = base;
    cursor[i] = base;
    base += c;
  }
  if (t == 1023) row_ptr[n] = partial[1023];
}

// CSR scatter: edge attrs re-ordered into CSR order as bf16.
__global__ __launch_bounds__(256) void scatter_kernel(
    const int* __restrict__ src, const int* __restrict__ dst,
    const float* __restrict__ eattr, int* __restrict__ cursor,
    int* __restrict__ esrc, unsigned short* __restrict__ ea16, int E)
{
  const int j = blockIdx.x * 256 + threadIdx.x;
  if (j < E) {
    const int p = atomicAdd(&cursor[dst[j]], 1);
    esrc[p] = src[j];
    const float4* ep = reinterpret_cast<const float4*>(&eattr[(size_t)j * DE]);
    const float4 e0 = ep[0], e1 = ep[1], e2 = ep[2], e3 = ep[3];
    const float ea[16] = {e0.x, e0.y, e0.z, e0.w, e1.x, e1.y, e1.z, e1.w,
                          e2.x, e2.y, e2.z, e2.w, e3.x, e3.y, e3.z, e3.w};
    s16x8 v0, v1;
    #pragma unroll
    for (int k = 0; k < 8; ++k) {
      v0[k] = (short)f2bf(ea[k]);
      v1[k] = (short)f2bf(ea[8 + k]);
    }
    s16x8* op = reinterpret_cast<s16x8*>(&ea16[(size_t)p * DE]);
    op[0] = v0; op[1] = v1;
  }
}

// ---------------- weight preprocessing: transpose + bf16 hi/lo split ----
__global__ __launch_bounds__(256) void convertW_kernel(
    const float* __restrict__ W_ne, const float* __restrict__ W_pre,
    const float* __restrict__ W1_a, const float* __restrict__ W2_a,
    const float* __restrict__ W1_l, const float* __restrict__ W2_l,
    unsigned short* __restrict__ hi, unsigned short* __restrict__ lo)
{
  const int mat = blockIdx.y;
  const float* src;
  int K = 256;
  if (mat == 0)      { src = W_ne;  K = 64; }
  else if (mat == 1) { src = W_pre; }
  else if (mat == 2) { src = W1_a; }
  else if (mat == 3) { src = W2_a; }
  else if (mat < 8)  { src = W1_l + (size_t)(mat - 4) * 65536; }
  else               { src = W2_l + (size_t)(mat - 8) * 65536; }
  const size_t off = woff(mat);

  const int ntiles = (K >> 6) * 4;
  const int t = blockIdx.x;
  if (t >= ntiles) return;
  const int tk = t % (K >> 6);
  const int tn = t / (K >> 6);

  __shared__ float tile[64][65];
  const int tid = threadIdx.x;
  const int c = tid & 63;
  const int rg = tid >> 6;
  for (int i = 0; i < 16; ++i) {
    const int r = rg + i * 4;
    tile[r][c] = src[(size_t)(tk * 64 + r) * 256 + tn * 64 + c];
  }
  __syncthreads();
  const int k = tk * 64 + c;
  for (int i = 0; i < 16; ++i) {
    const int nn = rg + i * 4;
    const int n = tn * 64 + nn;
    const float x = tile[c][nn];
    const unsigned short hh = f2bf(x);
    hi[off + (size_t)n * K + k] = hh;
    lo[off + (size_t)n * K + k] = f2bf(x - bf2f(hh));
  }
}

// W_ee[16,256] -> Wt16[256][16] bf16 (transposed)
__global__ __launch_bounds__(256) void convertWee_kernel(
    const float* __restrict__ Wee, unsigned short* __restrict__ Wt16)
{
  const int n = threadIdx.x;  // 0..255
  #pragma unroll
  for (int k = 0; k < DE; ++k)
    Wt16[n * DE + k] = f2bf(Wee[k * DM + n]);
}

// ---------------- edge encoder: e16[p] = ea16[p] @ W_ee + b_ee ----------
// LDS-staged coalesced output: 256 B contiguous per edge per block.
__global__ __launch_bounds__(256) void eenc_kernel(
    const unsigned short* __restrict__ ea16, const unsigned short* __restrict__ Wt16,
    const float* __restrict__ bee, unsigned short* __restrict__ e16)
{
  __shared__ unsigned short stage[128][136];  // +8 pad, rows 16B-aligned
  const int tid = threadIdx.x;
  const int lane = tid & 63, wid = tid >> 6;
  const int l15 = lane & 15, l4 = lane >> 4;
  const int eBase0 = blockIdx.x * 128;
  const int eBase = eBase0 + wid * 32;
  const int colBase = blockIdx.y * 128;
  const s16x8 zz = {0, 0, 0, 0, 0, 0, 0, 0};

  s16x8 ah[2];
  #pragma unroll
  for (int mi = 0; mi < 2; ++mi) {
    const int edge = eBase + mi * 16 + l15;
    ah[mi] = (l4 < 2)
        ? *reinterpret_cast<const s16x8*>(&ea16[(size_t)edge * DE + l4 * 8]) : zz;
  }
  s16x8 bh[8];
  #pragma unroll
  for (int ni = 0; ni < 8; ++ni) {
    const int col = colBase + ni * 16 + l15;
    bh[ni] = (l4 < 2)
        ? *reinterpret_cast<const s16x8*>(&Wt16[col * DE + l4 * 8]) : zz;
  }
  f32x4 acc[2][8];
  #pragma unroll
  for (int mi = 0; mi < 2; ++mi)
    #pragma unroll
    for (int ni = 0; ni < 8; ++ni)
      acc[mi][ni] = (f32x4){0.f, 0.f, 0.f, 0.f};
  #pragma unroll
  for (int mi = 0; mi < 2; ++mi)
    #pragma unroll
    for (int ni = 0; ni < 8; ++ni)
      acc[mi][ni] = __builtin_amdgcn_mfma_f32_16x16x32_bf16(ah[mi], bh[ni], acc[mi][ni], 0, 0, 0);

  #pragma unroll
  for (int ni = 0; ni < 8; ++ni) {
    const int col = ni * 16 + l15;
    const float bv = bee[colBase + col];
    #pragma unroll
    for (int mi = 0; mi < 2; ++mi) {
      #pragma unroll
      for (int r = 0; r < 4; ++r) {
        const int erow = wid * 32 + mi * 16 + l4 * 4 + r;
        stage[erow][col] = f2bf(acc[mi][ni][r] + bv);
      }
    }
  }
  __syncthreads();
  // coalesced out: 16 threads x 16 B = 256 B contiguous per edge
  #pragma unroll
  for (int it = 0; it < 8; ++it) {
    const int idx = tid + it * 256;
    const int e = idx >> 4, cc = idx & 15;
    const s16x8 v = *reinterpret_cast<const s16x8*>(&stage[e][cc * 8]);
    *reinterpret_cast<s16x8*>(&e16[(size_t)(eBase0 + e) * DM + colBase + cc * 8]) = v;
  }
}

// ---------------- MFMA matmul: BM=64 BN=128, all-bf16 activations --------
// ABF16: A is bf16 [M,K] (2-term MFMA). else fp32 A, split hi/lo (3-term).
// RESID: O16 = f2bf(bf2f(O16_old) + v).
template<bool RELU, bool RESID, bool ABF16>
__global__ __launch_bounds__(256) void mm_mfma(
    const float* __restrict__ Af, const unsigned short* __restrict__ Ab,
    const unsigned short* __restrict__ Bth, const unsigned short* __restrict__ Btl,
    const float* __restrict__ bias,
    unsigned short* __restrict__ O16, int M, int K)
{
  __shared__ unsigned short Ah[64 * 64];
  __shared__ unsigned short Al[ABF16 ? 8 : 64 * 64];
  __shared__ unsigned short Bh[128 * 64], Bl[128 * 64];
  const int tid = threadIdx.x;
  const int lane = tid & 63, wid = tid >> 6;
  const int wr = wid >> 1, wc = wid & 1;
  const int l15 = lane & 15, l4 = lane >> 4;
  const int rowBase = blockIdx.x * 64, colBase = blockIdx.y * 128;

  f32x4 acc[2][4];
  #pragma unroll
  for (int i = 0; i < 2; ++i)
    #pragma unroll
    for (int j = 0; j < 4; ++j) acc[i][j] = (f32x4){0.f, 0.f, 0.f, 0.f};

  const int nk = K >> 6;
  for (int ks = 0; ks < nk; ++ks) {
    // stage A
    #pragma unroll
    for (int i = 0; i < 2; ++i) {
      const int u = tid + i * 256;
      const int row = u >> 3, kc = u & 7;
      const int grow = rowBase + row;
      const int chunk = row * 8 + (kc ^ (row & 7));
      if (ABF16) {
        s16x8 v = {0, 0, 0, 0, 0, 0, 0, 0};
        if (grow < M)
          v = *reinterpret_cast<const s16x8*>(&Ab[(size_t)grow * K + ks * 64 + kc * 8]);
        ((s16x8*)Ah)[chunk] = v;
      } else {
        float4 v0 = make_float4(0.f, 0.f, 0.f, 0.f), v1 = v0;
        if (grow < M) {
          const float* p = Af + (size_t)grow * K + ks * 64 + kc * 8;
          v0 = *reinterpret_cast<const float4*>(p);
          v1 = *reinterpret_cast<const float4*>(p + 4);
        }
        const float xs[8] = {v0.x, v0.y, v0.z, v0.w, v1.x, v1.y, v1.z, v1.w};
        s16x8 hv, lv;
        #pragma unroll
        for (int j = 0; j < 8; ++j) {
          const unsigned short hh = f2bf(xs[j]);
          hv[j] = (short)hh;
          lv[j] = (short)f2bf(xs[j] - bf2f(hh));
        }
        ((s16x8*)Ah)[chunk] = hv;
        ((s16x8*)Al)[chunk] = lv;
      }
    }
    // stage B: 128 n x 64 k
    #pragma unroll
    for (int i = 0; i < 4; ++i) {
      const int u = tid + i * 256;
      const int n = u >> 3, kc = u & 7;
      const size_t g = (size_t)(colBase + n) * K + ks * 64 + kc * 8;
      const int chunk = n * 8 + (kc ^ (n & 7));
      ((s16x8*)Bh)[chunk] = *reinterpret_cast<const s16x8*>(Bth + g);
      ((s16x8*)Bl)[chunk] = *reinterpret_cast<const s16x8*>(Btl + g);
    }
    __syncthreads();
    #pragma unroll
    for (int sub = 0; sub < 2; ++sub) {
      const int kc = sub * 4 + l4;
      s16x8 ah[2], al[2], bh[4], bl[4];
      #pragma unroll
      for (int mi = 0; mi < 2; ++mi) {
        const int r = wr * 32 + mi * 16 + l15;
        const int ch = r * 8 + (kc ^ (r & 7));
        ah[mi] = ((const s16x8*)Ah)[ch];
        if (!ABF16) al[mi] = ((const s16x8*)Al)[ch];
      }
      #pragma unroll
      for (int ni = 0; ni < 4; ++ni) {
        const int r = wc * 64 + ni * 16 + l15;
        const int ch = r * 8 + (kc ^ (r & 7));
        bh[ni] = ((const s16x8*)Bh)[ch];
        bl[ni] = ((const s16x8*)Bl)[ch];
      }
      #pragma unroll
      for (int mi = 0; mi < 2; ++mi)
        #pragma unroll
        for (int ni = 0; ni < 4; ++ni) {
          acc[mi][ni] = __builtin_amdgcn_mfma_f32_16x16x32_bf16(ah[mi], bh[ni], acc[mi][ni], 0, 0, 0);
          acc[mi][ni] = __builtin_amdgcn_mfma_f32_16x16x32_bf16(ah[mi], bl[ni], acc[mi][ni], 0, 0, 0);
          if (!ABF16)
            acc[mi][ni] = __builtin_amdgcn_mfma_f32_16x16x32_bf16(al[mi], bh[ni], acc[mi][ni], 0, 0, 0);
        }
    }
    __syncthreads();
  }

  #pragma unroll
  for (int ni = 0; ni < 4; ++ni) {
    const int gcol = colBase + wc * 64 + ni * 16 + l15;
    const float bv = bias[gcol];
    #pragma unroll
    for (int mi = 0; mi < 2; ++mi) {
      const int rbase = rowBase + wr * 32 + mi * 16 + l4 * 4;
      #pragma unroll
      for (int r = 0; r < 4; ++r) {
        const int grow = rbase + r;
        if (grow < M) {
          float v = acc[mi][ni][r] + bv;
          if (RESID) v += bf2f(O16[(size_t)grow * DM + gcol]);
          if (RELU) v = fmaxf(v, 0.f);
          O16[(size_t)grow * DM + gcol] = f2bf(v);
        }
      }
    }
  }
}

// ---------------- gather v5: half-wave edge pairs, 16B loads --------
// lanes 0-31 process even edges, 32-63 odd; each lane owns 8 channels.
__global__ __launch_bounds__(256) void gather_e16_kernel(
    const unsigned short* __restrict__ h16,
    const int* __restrict__ row_ptr, const int* __restrict__ esrc,
    const unsigned short* __restrict__ e16,
    const float* __restrict__ eps_ptr, int eps_idx,
    unsigned short* __restrict__ out16, int n)
{
  const int tid = threadIdx.x;
  const int lane = tid & 63, wave = tid >> 6;
  const int half = lane >> 5;
  const int c8 = (lane & 31) * 8;
  const float ep1 = 1.0f + eps_ptr[eps_idx];
  const int stride = gridDim.x * 4;

  for (int i = blockIdx.x * 4 + wave; i < n; i += stride) {
    const int beg = row_ptr[i], end = row_ptr[i + 1];
    const int cnt = end - beg;
    float a[8];
    #pragma unroll
    for (int k = 0; k < 8; ++k) a[k] = 0.f;

    const int npair = cnt >> 1;
    int it = 0;
    for (; it + 2 <= npair; it += 2) {
      const int p0 = beg + 2 * it + half;
      const int p1 = p0 + 2;
      const int s0 = esrc[p0], s1 = esrc[p1];
      const s16x8 h0 = *reinterpret_cast<const s16x8*>(&h16[(size_t)s0 * DM + c8]);
      const s16x8 e0 = *reinterpret_cast<const s16x8*>(&e16[(size_t)p0 * DM + c8]);
      const s16x8 h1 = *reinterpret_cast<const s16x8*>(&h16[(size_t)s1 * DM + c8]);
      const s16x8 e1 = *reinterpret_cast<const s16x8*>(&e16[(size_t)p1 * DM + c8]);
      #pragma unroll
      for (int k = 0; k < 8; ++k) {
        a[k] += fmaxf(bf2f((unsigned short)h0[k]) + bf2f((unsigned short)e0[k]), 0.f);
        a[k] += fmaxf(bf2f((unsigned short)h1[k]) + bf2f((unsigned short)e1[k]), 0.f);
      }
    }
    for (; it < npair; ++it) {
      const int p0 = beg + 2 * it + half;
      const int s0 = esrc[p0];
      const s16x8 h0 = *reinterpret_cast<const s16x8*>(&h16[(size_t)s0 * DM + c8]);
      const s16x8 e0 = *reinterpret_cast<const s16x8*>(&e16[(size_t)p0 * DM + c8]);
      #pragma unroll
      for (int k = 0; k < 8; ++k)
        a[k] += fmaxf(bf2f((unsigned short)h0[k]) + bf2f((unsigned short)e0[k]), 0.f);
    }
    if ((cnt & 1) && half == 0) {
      const int p0 = end - 1;
      const int s0 = esrc[p0];
      const s16x8 h0 = *reinterpret_cast<const s16x8*>(&h16[(size_t)s0 * DM + c8]);
      const s16x8 e0 = *reinterpret_cast<const s16x8*>(&e16[(size_t)p0 * DM + c8]);
      #pragma unroll
      for (int k = 0; k < 8; ++k)
        a[k] += fmaxf(bf2f((unsigned short)h0[k]) + bf2f((unsigned short)e0[k]), 0.f);
    }
    // combine the two half-wave accumulators
    #pragma unroll
    for (int k = 0; k < 8; ++k) a[k] += __shfl_xor(a[k], 32, 64);
    if (half == 0) {
      const s16x8 hs = *reinterpret_cast<const s16x8*>(&h16[(size_t)i * DM + c8]);
      s16x8 o;
      #pragma unroll
      for (int k = 0; k < 8; ++k)
        o[k] = (short)f2bf(ep1 * bf2f((unsigned short)hs[k]) + a[k]);
      *reinterpret_cast<s16x8*>(&out16[(size_t)i * DM + c8]) = o;
    }
  }
}

// ---------------- gather fallback: recompute e per edge -------
__global__ __launch_bounds__(256) void gather_rc_kernel(
    const unsigned short* __restrict__ h16,
    const int* __restrict__ row_ptr, const int* __restrict__ esrc,
    const unsigned short* __restrict__ ea16,
    const float* __restrict__ Wee, const float* __restrict__ bee,
    const float* __restrict__ eps_ptr, int eps_idx,
    unsigned short* __restrict__ out16, int n)
{
  const int tid = threadIdx.x;
  const int lane = tid & 63, wave = tid >> 6;
  const int c4 = lane * 4;
  float4 w[16];
  #pragma unroll
  for (int k = 0; k < 16; ++k)
    w[k] = *reinterpret_cast<const float4*>(&Wee[k * DM + c4]);
  const float4 bv = *reinterpret_cast<const float4*>(&bee[c4]);
  const float ep1 = 1.0f + eps_ptr[eps_idx];
  const int stride = gridDim.x * 4;

  for (int i = blockIdx.x * 4 + wave; i < n; i += stride) {
    const int beg = row_ptr[i], end = row_ptr[i + 1];
    float a0 = 0.f, a1 = 0.f, a2 = 0.f, a3 = 0.f;
    for (int p = beg; p < end; ++p) {
      const int s = esrc[p];
      const ushort4 hv = *reinterpret_cast<const ushort4*>(&h16[(size_t)s * DM + c4]);
      const s16x8* eap = reinterpret_cast<const s16x8*>(&ea16[(size_t)p * DE]);
      const s16x8 ew0 = eap[0], ew1 = eap[1];
      float m0 = bf2f(hv.x) + bv.x, m1 = bf2f(hv.y) + bv.y;
      float m2 = bf2f(hv.z) + bv.z, m3 = bf2f(hv.w) + bv.w;
      float ea[16];
      #pragma unroll
      for (int k = 0; k < 8; ++k) {
        ea[k] = bf2f((unsigned short)ew0[k]);
        ea[8 + k] = bf2f((unsigned short)ew1[k]);
      }
      #pragma unroll
      for (int k = 0; k < 16; ++k) {
        m0 += ea[k] * w[k].x; m1 += ea[k] * w[k].y;
        m2 += ea[k] * w[k].z; m3 += ea[k] * w[k].w;
      }
      a0 += fmaxf(m0, 0.f); a1 += fmaxf(m1, 0.f);
      a2 += fmaxf(m2, 0.f); a3 += fmaxf(m3, 0.f);
    }
    const ushort4 hs = *reinterpret_cast<const ushort4*>(&h16[(size_t)i * DM + c4]);
    ushort4 o;
    o.x = f2bf(ep1 * bf2f(hs.x) + a0); o.y = f2bf(ep1 * bf2f(hs.y) + a1);
    o.z = f2bf(ep1 * bf2f(hs.z) + a2); o.w = f2bf(ep1 * bf2f(hs.w) + a3);
    *reinterpret_cast<ushort4*>(&out16[(size_t)i * DM + c4]) = o;
  }
}

// out[M,10] = h16[M,256] @ W[256,10] + b
__global__ __launch_bounds__(256) void head_kernel(
    const unsigned short* __restrict__ h16, const float* __restrict__ W,
    const float* __restrict__ b, float* __restrict__ out, int M)
{
  __shared__ float Ws[DM * DO];
  const int tid = threadIdx.x;
  for (int i = tid; i < DM * DO; i += 256) Ws[i] = W[i];
  __syncthreads();
  const int r = tid >> 4;
  const int c = tid & 15;
  const int row = blockIdx.x * 16 + r;
  if (row < M && c < DO) {
    const unsigned short* hp = &h16[(size_t)row * DM];
    float acc = 0.f;
    #pragma unroll 8
    for (int k = 0; k < DM; ++k) acc += bf2f(hp[k]) * Ws[k * DO + c];
    out[(size_t)row * DO + c] = acc + b[c];
  }
}

}  // namespace

extern "C" void kernel_launch(void* const* d_in, const int* in_sizes, int n_in,
                              void* d_out, int out_size, void* d_ws, size_t ws_size,
                              hipStream_t stream) {
  const float* x     = (const float*)d_in[0];
  const float* eattr = (const float*)d_in[1];
  const int*   eidx  = (const int*)d_in[2];
  const float* W_ne  = (const float*)d_in[3];
  const float* b_ne  = (const float*)d_in[4];
  const float* W_ee  = (const float*)d_in[5];
  const float* b_ee  = (const float*)d_in[6];
  const float* W_pre = (const float*)d_in[7];
  const float* b_pre = (const float*)d_in[8];
  const float* eps_a = (const float*)d_in[9];
  const float* W1_a  = (const float*)d_in[10];
  const float* b1_a  = (const float*)d_in[11];
  const float* W2_a  = (const float*)d_in[12];
  const float* b2_a  = (const float*)d_in[13];
  const float* eps_l = (const float*)d_in[14];
  const float* W1_l  = (const float*)d_in[15];
  const float* b1_l  = (const float*)d_in[16];
  const float* W2_l  = (const float*)d_in[17];
  const float* b2_l  = (const float*)d_in[18];
  const float* W_h   = (const float*)d_in[19];
  const float* b_h   = (const float*)d_in[20];

  const int* src = eidx;
  const int* dst = eidx + NE;

  // workspace layout (e16 LAST; fallback path needs none of it)
  char* wp = (char*)d_ws;
  unsigned short* h16   = (unsigned short*)wp; wp += (size_t)NN * DM * 2;
  unsigned short* t16   = (unsigned short*)wp; wp += (size_t)NN * DM * 2;
  unsigned short* agg16 = (unsigned short*)wp; wp += (size_t)NN * DM * 2;
  unsigned short* ea16  = (unsigned short*)wp; wp += (size_t)NE * DE * 2;
  unsigned short* wt_hi = (unsigned short*)wp; wp += WTOTAL * 2;
  unsigned short* wt_lo = (unsigned short*)wp; wp += WTOTAL * 2;
  unsigned short* wtee  = (unsigned short*)wp; wp += (size_t)DM * DE * 2;
  int* esrc    = (int*)wp;                     wp += (size_t)NE * 4;
  int* counts  = (int*)wp;                     wp += (size_t)NN * 4;
  int* row_ptr = (int*)wp;                     wp += (size_t)(NN + 1) * 4;
  int* cursor  = (int*)wp;                     wp += (size_t)NN * 4;
  wp = (char*)(((uintptr_t)wp + 15) & ~(uintptr_t)15);
  unsigned short* e16 = (unsigned short*)wp;
  const size_t need_e16 = (size_t)(wp - (char*)d_ws) + (size_t)NE * DM * 2;
  const bool use_e16 = ws_size >= need_e16;

  // ---- CSR build ----
  hipMemsetAsync(counts, 0, NN * sizeof(int), stream);
  hist_kernel<<<(NE + 255) / 256, 256, 0, stream>>>(dst, counts, NE);
  scan_kernel<<<1, 1024, 0, stream>>>(counts, row_ptr, cursor, NN);
  scatter_kernel<<<(NE + 255) / 256, 256, 0, stream>>>(
      src, dst, eattr, cursor, esrc, ea16, NE);

  // ---- weight preprocessing ----
  convertW_kernel<<<dim3(16, 12), 256, 0, stream>>>(
      W_ne, W_pre, W1_a, W2_a, W1_l, W2_l, wt_hi, wt_lo);
  convertWee_kernel<<<1, 256, 0, stream>>>(W_ee, wtee);

  // ---- edge encoder (layer-invariant), once ----
  if (use_e16)
    eenc_kernel<<<dim3(NE / 128, 2), 256, 0, stream>>>(ea16, wtee, b_ee, e16);

  const dim3 mmgrid((NN + 63) / 64, 2);

  // encoder: t16 = x @ W_ne + b_ne   (K=64, fp32 A)
  mm_mfma<false, false, false><<<mmgrid, 256, 0, stream>>>(
      x, nullptr, wt_hi + woff(0), wt_lo + woff(0), b_ne, t16, NN, DI);
  // pre-MP: h16 = relu(t16 @ W_pre + b_pre)
  mm_mfma<true, false, true><<<mmgrid, 256, 0, stream>>>(
      nullptr, t16, wt_hi + woff(1), wt_lo + woff(1), b_pre, h16, NN, DM);

  for (int layer = 0; layer < 5; ++layer) {
    const float* eps; int ei; const float *b1, *b2; size_t o1, o2; bool resid;
    if (layer == 0) {
      eps = eps_a; ei = 0; b1 = b1_a; b2 = b2_a;
      o1 = woff(2); o2 = woff(3); resid = false;
    } else {
      const int i = layer - 1;
      eps = eps_l; ei = i;
      b1 = b1_l + (size_t)i * DM; b2 = b2_l + (size_t)i * DM;
      o1 = woff(4 + i); o2 = woff(8 + i); resid = true;
    }
    if (use_e16)
      gather_e16_kernel<<<2500, 256, 0, stream>>>(
          h16, row_ptr, esrc, e16, eps, ei, agg16, NN);
    else
      gather_rc_kernel<<<1280, 256, 0, stream>>>(
          h16, row_ptr, esrc, ea16, W_ee, b_ee, eps, ei, agg16, NN);
    // t16 = relu(agg16 @ W1 + b1)
    mm_mfma<true, false, true><<<mmgrid, 256, 0, stream>>>(
        nullptr, agg16, wt_hi + o1, wt_lo + o1, b1, t16, NN, DM);
    // h16 = [h16 +] t16 @ W2 + b2
    if (resid)
      mm_mfma<false, true, true><<<mmgrid, 256, 0, stream>>>(
          nullptr, t16, wt_hi + o2, wt_lo + o2, b2, h16, NN, DM);
    else
      mm_mfma<false, false, true><<<mmgrid, 256, 0, stream>>>(
          nullptr, t16, wt_hi + o2, wt_lo + o2, b2, h16, NN, DM);
  }

  head_kernel<<<(NN + 15) / 16, 256, 0, stream>>>(h16, W_h, b_h, (float*)d_out, NN);
}

// Round 9
// 514.091 us; speedup vs baseline: 11.6302x; 1.0986x over previous
//
#include <hip/hip_runtime.h>
#include <hip/hip_bf16.h>

namespace {

constexpr int NN = 20000;   // nodes
constexpr int NE = 320000;  // edges
constexpr int DI = 64;      // input node dim
constexpr int DE = 16;      // edge attr dim
constexpr int DM = 256;     // hidden dim
constexpr int DO = 10;      // out dim

// weight-plane offsets: mat 0 = W_ne (64*256), mats 1..11 = 256*256 each
__host__ __device__ constexpr size_t woff(int m) {
  return m == 0 ? 0 : (size_t)16384 + (size_t)(m - 1) * 65536;
}
constexpr size_t WTOTAL = 16384 + 11 * 65536;

typedef __attribute__((ext_vector_type(8))) short s16x8;
typedef __attribute__((ext_vector_type(4))) float f32x4;

__device__ inline unsigned short f2bf(float x) {
  union { float f; unsigned u; } c; c.f = x;
  unsigned r = (c.u + 0x7FFFu + ((c.u >> 16) & 1u)) >> 16;
  return (unsigned short)r;
}
__device__ inline float bf2f(unsigned short h) {
  union { unsigned u; float f; } c; c.u = ((unsigned)h) << 16;
  return c.f;
}

// fp32 -> OCP e4m3fn, RTNE, flush-to-zero below 2^-7 (no subnormals emitted).
__device__ inline unsigned char f2e4m3(float x) {
  union { float f; unsigned u; } c; c.f = x;
  const unsigned s = (c.u >> 24) & 0x80u;
  float ax = fabsf(x);
  if (ax < 0.0078125f) return (unsigned char)s;          // flush to +-0
  if (ax > 448.f) ax = 448.f;                            // clamp to max finite
  c.f = ax;
  unsigned b = c.u;
  b += 0x7FFFFu + ((b >> 20) & 1u);                      // RTNE at bit 20
  const unsigned e8 = (b >> 23) - 120u;                  // bias 127 -> 7
  const unsigned m8 = (b >> 20) & 7u;
  return (unsigned char)(s | (e8 << 3) | m8);
}
// e4m3fn -> fp32; exact for normals (encoder emits only normals/zero).
__device__ inline float e4m32f(unsigned u) {
  unsigned b = ((u & 0x80u) << 24) | (((u & 0x7Fu) << 20) + 0x3C000000u);
  if ((u & 0x7Fu) == 0) b &= 0x80000000u;                // true zero
  union { unsigned u; float f; } c; c.u = b;
  return c.f;
}

// ---------------- CSR build (counting sort by dst) ----------------

__global__ __launch_bounds__(256) void hist_kernel(
    const int* __restrict__ dst, int* __restrict__ counts, int E)
{
  const int j = blockIdx.x * 256 + threadIdx.x;
  if (j < E) atomicAdd(&counts[dst[j]], 1);
}

__global__ __launch_bounds__(1024) void scan_kernel(
    const int* __restrict__ counts, int* __restrict__ row_ptr,
    int* __restrict__ cursor, int n)
{
  __shared__ int partial[1024];
  const int t = threadIdx.x;
  const int chunk = (n + 1023) / 1024;
  const int beg = t * chunk;
  const int end = min(beg + chunk, n);
  int s = 0;
  for (int i = beg; i < end; ++i) s += counts[i];
  partial[t] = s;
  __syncthreads();
  for (int off = 1; off < 1024; off <<= 1) {
    const int v = (t >= off) ? partial[t - off] : 0;
    __syncthreads();
    partial[t] += v;
    __syncthreads();
  }
  int base = (t == 0) ? 0 : partial[t - 1];
  for (int i = beg; i < end; ++i) {
    const int c = counts[i];
    row_ptr[i] = base;
    cursor[i] = base;
    base += c;
  }
  if (t == 1023) row_ptr[n] = partial[1023];
}

// CSR scatter: edge attrs re-ordered into CSR order as bf16.
__global__ __launch_bounds__(256) void scatter_kernel(
    const int* __restrict__ src, const int* __restrict__ dst,
    const float* __restrict__ eattr, int* __restrict__ cursor,
    int* __restrict__ esrc, unsigned short* __restrict__ ea16, int E)
{
  const int j = blockIdx.x * 256 + threadIdx.x;
  if (j < E) {
    const int p = atomicAdd(&cursor[dst[j]], 1);
    esrc[p] = src[j];
    const float4* ep = reinterpret_cast<const float4*>(&eattr[(size_t)j * DE]);
    const float4 e0 = ep[0], e1 = ep[1], e2 = ep[2], e3 = ep[3];
    const float ea[16] = {e0.x, e0.y, e0.z, e0.w, e1.x, e1.y, e1.z, e1.w,
                          e2.x, e2.y, e2.z, e2.w, e3.x, e3.y, e3.z, e3.w};
    s16x8 v0, v1;
    #pragma unroll
    for (int k = 0; k < 8; ++k) {
      v0[k] = (short)f2bf(ea[k]);
      v1[k] = (short)f2bf(ea[8 + k]);
    }
    s16x8* op = reinterpret_cast<s16x8*>(&ea16[(size_t)p * DE]);
    op[0] = v0; op[1] = v1;
  }
}

// ---------------- weight preprocessing: transpose + bf16 hi/lo split ----
__global__ __launch_bounds__(256) void convertW_kernel(
    const float* __restrict__ W_ne, const float* __restrict__ W_pre,
    const float* __restrict__ W1_a, const float* __restrict__ W2_a,
    const float* __restrict__ W1_l, const float* __restrict__ W2_l,
    unsigned short* __restrict__ hi, unsigned short* __restrict__ lo)
{
  const int mat = blockIdx.y;
  const float* src;
  int K = 256;
  if (mat == 0)      { src = W_ne;  K = 64; }
  else if (mat == 1) { src = W_pre; }
  else if (mat == 2) { src = W1_a; }
  else if (mat == 3) { src = W2_a; }
  else if (mat < 8)  { src = W1_l + (size_t)(mat - 4) * 65536; }
  else               { src = W2_l + (size_t)(mat - 8) * 65536; }
  const size_t off = woff(mat);

  const int ntiles = (K >> 6) * 4;
  const int t = blockIdx.x;
  if (t >= ntiles) return;
  const int tk = t % (K >> 6);
  const int tn = t / (K >> 6);

  __shared__ float tile[64][65];
  const int tid = threadIdx.x;
  const int c = tid & 63;
  const int rg = tid >> 6;
  for (int i = 0; i < 16; ++i) {
    const int r = rg + i * 4;
    tile[r][c] = src[(size_t)(tk * 64 + r) * 256 + tn * 64 + c];
  }
  __syncthreads();
  const int k = tk * 64 + c;
  for (int i = 0; i < 16; ++i) {
    const int nn = rg + i * 4;
    const int n = tn * 64 + nn;
    const float x = tile[c][nn];
    const unsigned short hh = f2bf(x);
    hi[off + (size_t)n * K + k] = hh;
    lo[off + (size_t)n * K + k] = f2bf(x - bf2f(hh));
  }
}

// W_ee[16,256] -> Wt16[256][16] bf16 (transposed)
__global__ __launch_bounds__(256) void convertWee_kernel(
    const float* __restrict__ Wee, unsigned short* __restrict__ Wt16)
{
  const int n = threadIdx.x;  // 0..255
  #pragma unroll
  for (int k = 0; k < DE; ++k)
    Wt16[n * DE + k] = f2bf(Wee[k * DM + n]);
}

// ---------------- edge encoder: e8[p] = e4m3(ea16[p] @ W_ee + b_ee) -----
// LDS-staged coalesced output: 128 B contiguous per edge per block.
__global__ __launch_bounds__(256) void eenc_kernel(
    const unsigned short* __restrict__ ea16, const unsigned short* __restrict__ Wt16,
    const float* __restrict__ bee, unsigned char* __restrict__ e8)
{
  __shared__ unsigned char stage[128][144];  // rows 16B-aligned
  const int tid = threadIdx.x;
  const int lane = tid & 63, wid = tid >> 6;
  const int l15 = lane & 15, l4 = lane >> 4;
  const int eBase0 = blockIdx.x * 128;
  const int eBase = eBase0 + wid * 32;
  const int colBase = blockIdx.y * 128;
  const s16x8 zz = {0, 0, 0, 0, 0, 0, 0, 0};

  s16x8 ah[2];
  #pragma unroll
  for (int mi = 0; mi < 2; ++mi) {
    const int edge = eBase + mi * 16 + l15;
    ah[mi] = (l4 < 2)
        ? *reinterpret_cast<const s16x8*>(&ea16[(size_t)edge * DE + l4 * 8]) : zz;
  }
  s16x8 bh[8];
  #pragma unroll
  for (int ni = 0; ni < 8; ++ni) {
    const int col = colBase + ni * 16 + l15;
    bh[ni] = (l4 < 2)
        ? *reinterpret_cast<const s16x8*>(&Wt16[col * DE + l4 * 8]) : zz;
  }
  f32x4 acc[2][8];
  #pragma unroll
  for (int mi = 0; mi < 2; ++mi)
    #pragma unroll
    for (int ni = 0; ni < 8; ++ni)
      acc[mi][ni] = (f32x4){0.f, 0.f, 0.f, 0.f};
  #pragma unroll
  for (int mi = 0; mi < 2; ++mi)
    #pragma unroll
    for (int ni = 0; ni < 8; ++ni)
      acc[mi][ni] = __builtin_amdgcn_mfma_f32_16x16x32_bf16(ah[mi], bh[ni], acc[mi][ni], 0, 0, 0);

  #pragma unroll
  for (int ni = 0; ni < 8; ++ni) {
    const int col = ni * 16 + l15;
    const float bv = bee[colBase + col];
    #pragma unroll
    for (int mi = 0; mi < 2; ++mi) {
      #pragma unroll
      for (int r = 0; r < 4; ++r) {
        const int erow = wid * 32 + mi * 16 + l4 * 4 + r;
        stage[erow][col] = f2e4m3(acc[mi][ni][r] + bv);
      }
    }
  }
  __syncthreads();
  // coalesced out: 8 threads x 16 B = 128 B contiguous per edge
  #pragma unroll
  for (int it = 0; it < 4; ++it) {
    const int idx = tid + it * 256;
    const int e = idx >> 3, cc = idx & 7;
    const s16x8 v = *reinterpret_cast<const s16x8*>(&stage[e][cc * 16]);
    *reinterpret_cast<s16x8*>(&e8[(size_t)(eBase0 + e) * DM + colBase + cc * 16]) = v;
  }
}

// ---------------- MFMA matmul: BM=64 BN=128, all-bf16 activations --------
// ABF16: A is bf16 [M,K] (2-term MFMA). else fp32 A, split hi/lo (3-term).
// RESID: O16 = f2bf(bf2f(O16_old) + v).
template<bool RELU, bool RESID, bool ABF16>
__global__ __launch_bounds__(256) void mm_mfma(
    const float* __restrict__ Af, const unsigned short* __restrict__ Ab,
    const unsigned short* __restrict__ Bth, const unsigned short* __restrict__ Btl,
    const float* __restrict__ bias,
    unsigned short* __restrict__ O16, int M, int K)
{
  __shared__ unsigned short Ah[64 * 64];
  __shared__ unsigned short Al[ABF16 ? 8 : 64 * 64];
  __shared__ unsigned short Bh[128 * 64], Bl[128 * 64];
  const int tid = threadIdx.x;
  const int lane = tid & 63, wid = tid >> 6;
  const int wr = wid >> 1, wc = wid & 1;
  const int l15 = lane & 15, l4 = lane >> 4;
  const int rowBase = blockIdx.x * 64, colBase = blockIdx.y * 128;

  f32x4 acc[2][4];
  #pragma unroll
  for (int i = 0; i < 2; ++i)
    #pragma unroll
    for (int j = 0; j < 4; ++j) acc[i][j] = (f32x4){0.f, 0.f, 0.f, 0.f};

  const int nk = K >> 6;
  for (int ks = 0; ks < nk; ++ks) {
    // stage A
    #pragma unroll
    for (int i = 0; i < 2; ++i) {
      const int u = tid + i * 256;
      const int row = u >> 3, kc = u & 7;
      const int grow = rowBase + row;
      const int chunk = row * 8 + (kc ^ (row & 7));
      if (ABF16) {
        s16x8 v = {0, 0, 0, 0, 0, 0, 0, 0};
        if (grow < M)
          v = *reinterpret_cast<const s16x8*>(&Ab[(size_t)grow * K + ks * 64 + kc * 8]);
        ((s16x8*)Ah)[chunk] = v;
      } else {
        float4 v0 = make_float4(0.f, 0.f, 0.f, 0.f), v1 = v0;
        if (grow < M) {
          const float* p = Af + (size_t)grow * K + ks * 64 + kc * 8;
          v0 = *reinterpret_cast<const float4*>(p);
          v1 = *reinterpret_cast<const float4*>(p + 4);
        }
        const float xs[8] = {v0.x, v0.y, v0.z, v0.w, v1.x, v1.y, v1.z, v1.w};
        s16x8 hv, lv;
        #pragma unroll
        for (int j = 0; j < 8; ++j) {
          const unsigned short hh = f2bf(xs[j]);
          hv[j] = (short)hh;
          lv[j] = (short)f2bf(xs[j] - bf2f(hh));
        }
        ((s16x8*)Ah)[chunk] = hv;
        ((s16x8*)Al)[chunk] = lv;
      }
    }
    // stage B: 128 n x 64 k
    #pragma unroll
    for (int i = 0; i < 4; ++i) {
      const int u = tid + i * 256;
      const int n = u >> 3, kc = u & 7;
      const size_t g = (size_t)(colBase + n) * K + ks * 64 + kc * 8;
      const int chunk = n * 8 + (kc ^ (n & 7));
      ((s16x8*)Bh)[chunk] = *reinterpret_cast<const s16x8*>(Bth + g);
      ((s16x8*)Bl)[chunk] = *reinterpret_cast<const s16x8*>(Btl + g);
    }
    __syncthreads();
    #pragma unroll
    for (int sub = 0; sub < 2; ++sub) {
      const int kc = sub * 4 + l4;
      s16x8 ah[2], al[2], bh[4], bl[4];
      #pragma unroll
      for (int mi = 0; mi < 2; ++mi) {
        const int r = wr * 32 + mi * 16 + l15;
        const int ch = r * 8 + (kc ^ (r & 7));
        ah[mi] = ((const s16x8*)Ah)[ch];
        if (!ABF16) al[mi] = ((const s16x8*)Al)[ch];
      }
      #pragma unroll
      for (int ni = 0; ni < 4; ++ni) {
        const int r = wc * 64 + ni * 16 + l15;
        const int ch = r * 8 + (kc ^ (r & 7));
        bh[ni] = ((const s16x8*)Bh)[ch];
        bl[ni] = ((const s16x8*)Bl)[ch];
      }
      #pragma unroll
      for (int mi = 0; mi < 2; ++mi)
        #pragma unroll
        for (int ni = 0; ni < 4; ++ni) {
          acc[mi][ni] = __builtin_amdgcn_mfma_f32_16x16x32_bf16(ah[mi], bh[ni], acc[mi][ni], 0, 0, 0);
          acc[mi][ni] = __builtin_amdgcn_mfma_f32_16x16x32_bf16(ah[mi], bl[ni], acc[mi][ni], 0, 0, 0);
          if (!ABF16)
            acc[mi][ni] = __builtin_amdgcn_mfma_f32_16x16x32_bf16(al[mi], bh[ni], acc[mi][ni], 0, 0, 0);
        }
    }
    __syncthreads();
  }

  #pragma unroll
  for (int ni = 0; ni < 4; ++ni) {
    const int gcol = colBase + wc * 64 + ni * 16 + l15;
    const float bv = bias[gcol];
    #pragma unroll
    for (int mi = 0; mi < 2; ++mi) {
      const int rbase = rowBase + wr * 32 + mi * 16 + l4 * 4;
      #pragma unroll
      for (int r = 0; r < 4; ++r) {
        const int grow = rbase + r;
        if (grow < M) {
          float v = acc[mi][ni][r] + bv;
          if (RESID) v += bf2f(O16[(size_t)grow * DM + gcol]);
          if (RELU) v = fmaxf(v, 0.f);
          O16[(size_t)grow * DM + gcol] = f2bf(v);
        }
      }
    }
  }
}

// ---------------- gather v6: fp8 e, half-wave pairs, 4-deep unroll ------
__global__ __launch_bounds__(256) void gather_e8_kernel(
    const unsigned short* __restrict__ h16,
    const int* __restrict__ row_ptr, const int* __restrict__ esrc,
    const unsigned char* __restrict__ e8,
    const float* __restrict__ eps_ptr, int eps_idx,
    unsigned short* __restrict__ out16, int n)
{
  const int tid = threadIdx.x;
  const int lane = tid & 63, wave = tid >> 6;
  const int half = lane >> 5;
  const int c8 = (lane & 31) * 8;
  const float ep1 = 1.0f + eps_ptr[eps_idx];
  const int stride = gridDim.x * 4;

  for (int i = blockIdx.x * 4 + wave; i < n; i += stride) {
    const int beg = row_ptr[i], end = row_ptr[i + 1];
    const int cnt = end - beg;
    float a[8];
    #pragma unroll
    for (int k = 0; k < 8; ++k) a[k] = 0.f;

    const int npair = cnt >> 1;
    int it = 0;
    for (; it + 4 <= npair; it += 4) {
      int pp[4], ss[4];
      #pragma unroll
      for (int j = 0; j < 4; ++j) {
        pp[j] = beg + 2 * (it + j) + half;
        ss[j] = esrc[pp[j]];
      }
      s16x8 hv[4]; uint2 ev[4];
      #pragma unroll
      for (int j = 0; j < 4; ++j) {
        hv[j] = *reinterpret_cast<const s16x8*>(&h16[(size_t)ss[j] * DM + c8]);
        ev[j] = *reinterpret_cast<const uint2*>(&e8[(size_t)pp[j] * DM + c8]);
      }
      #pragma unroll
      for (int j = 0; j < 4; ++j) {
        #pragma unroll
        for (int k = 0; k < 4; ++k) {
          a[k]     += fmaxf(bf2f((unsigned short)hv[j][k])     + e4m32f((ev[j].x >> (8 * k)) & 255u), 0.f);
          a[k + 4] += fmaxf(bf2f((unsigned short)hv[j][k + 4]) + e4m32f((ev[j].y >> (8 * k)) & 255u), 0.f);
        }
      }
    }
    for (; it < npair; ++it) {
      const int p0 = beg + 2 * it + half;
      const int s0 = esrc[p0];
      const s16x8 h0 = *reinterpret_cast<const s16x8*>(&h16[(size_t)s0 * DM + c8]);
      const uint2 e0 = *reinterpret_cast<const uint2*>(&e8[(size_t)p0 * DM + c8]);
      #pragma unroll
      for (int k = 0; k < 4; ++k) {
        a[k]     += fmaxf(bf2f((unsigned short)h0[k])     + e4m32f((e0.x >> (8 * k)) & 255u), 0.f);
        a[k + 4] += fmaxf(bf2f((unsigned short)h0[k + 4]) + e4m32f((e0.y >> (8 * k)) & 255u), 0.f);
      }
    }
    if ((cnt & 1) && half == 0) {
      const int p0 = end - 1;
      const int s0 = esrc[p0];
      const s16x8 h0 = *reinterpret_cast<const s16x8*>(&h16[(size_t)s0 * DM + c8]);
      const uint2 e0 = *reinterpret_cast<const uint2*>(&e8[(size_t)p0 * DM + c8]);
      #pragma unroll
      for (int k = 0; k < 4; ++k) {
        a[k]     += fmaxf(bf2f((unsigned short)h0[k])     + e4m32f((e0.x >> (8 * k)) & 255u), 0.f);
        a[k + 4] += fmaxf(bf2f((unsigned short)h0[k + 4]) + e4m32f((e0.y >> (8 * k)) & 255u), 0.f);
      }
    }
    // combine the two half-wave accumulators
    #pragma unroll
    for (int k = 0; k < 8; ++k) a[k] += __shfl_xor(a[k], 32, 64);
    if (half == 0) {
      const s16x8 hs = *reinterpret_cast<const s16x8*>(&h16[(size_t)i * DM + c8]);
      s16x8 o;
      #pragma unroll
      for (int k = 0; k < 8; ++k)
        o[k] = (short)f2bf(ep1 * bf2f((unsigned short)hs[k]) + a[k]);
      *reinterpret_cast<s16x8*>(&out16[(size_t)i * DM + c8]) = o;
    }
  }
}

// ---------------- gather fallback: recompute e per edge -------
__global__ __launch_bounds__(256) void gather_rc_kernel(
    const unsigned short* __restrict__ h16,
    const int* __restrict__ row_ptr, const int* __restrict__ esrc,
    const unsigned short* __restrict__ ea16,
    const float* __restrict__ Wee, const float* __restrict__ bee,
    const float* __restrict__ eps_ptr, int eps_idx,
    unsigned short* __restrict__ out16, int n)
{
  const int tid = threadIdx.x;
  const int lane = tid & 63, wave = tid >> 6;
  const int c4 = lane * 4;
  float4 w[16];
  #pragma unroll
  for (int k = 0; k < 16; ++k)
    w[k] = *reinterpret_cast<const float4*>(&Wee[k * DM + c4]);
  const float4 bv = *reinterpret_cast<const float4*>(&bee[c4]);
  const float ep1 = 1.0f + eps_ptr[eps_idx];
  const int stride = gridDim.x * 4;

  for (int i = blockIdx.x * 4 + wave; i < n; i += stride) {
    const int beg = row_ptr[i], end = row_ptr[i + 1];
    float a0 = 0.f, a1 = 0.f, a2 = 0.f, a3 = 0.f;
    for (int p = beg; p < end; ++p) {
      const int s = esrc[p];
      const ushort4 hv = *reinterpret_cast<const ushort4*>(&h16[(size_t)s * DM + c4]);
      const s16x8* eap = reinterpret_cast<const s16x8*>(&ea16[(size_t)p * DE]);
      const s16x8 ew0 = eap[0], ew1 = eap[1];
      float m0 = bf2f(hv.x) + bv.x, m1 = bf2f(hv.y) + bv.y;
      float m2 = bf2f(hv.z) + bv.z, m3 = bf2f(hv.w) + bv.w;
      float ea[16];
      #pragma unroll
      for (int k = 0; k < 8; ++k) {
        ea[k] = bf2f((unsigned short)ew0[k]);
        ea[8 + k] = bf2f((unsigned short)ew1[k]);
      }
      #pragma unroll
      for (int k = 0; k < 16; ++k) {
        m0 += ea[k] * w[k].x; m1 += ea[k] * w[k].y;
        m2 += ea[k] * w[k].z; m3 += ea[k] * w[k].w;
      }
      a0 += fmaxf(m0, 0.f); a1 += fmaxf(m1, 0.f);
      a2 += fmaxf(m2, 0.f); a3 += fmaxf(m3, 0.f);
    }
    const ushort4 hs = *reinterpret_cast<const ushort4*>(&h16[(size_t)i * DM + c4]);
    ushort4 o;
    o.x = f2bf(ep1 * bf2f(hs.x) + a0); o.y = f2bf(ep1 * bf2f(hs.y) + a1);
    o.z = f2bf(ep1 * bf2f(hs.z) + a2); o.w = f2bf(ep1 * bf2f(hs.w) + a3);
    *reinterpret_cast<ushort4*>(&out16[(size_t)i * DM + c4]) = o;
  }
}

// out[M,10] = h16[M,256] @ W[256,10] + b
__global__ __launch_bounds__(256) void head_kernel(
    const unsigned short* __restrict__ h16, const float* __restrict__ W,
    const float* __restrict__ b, float* __restrict__ out, int M)
{
  __shared__ float Ws[DM * DO];
  const int tid = threadIdx.x;
  for (int i = tid; i < DM * DO; i += 256) Ws[i] = W[i];
  __syncthreads();
  const int r = tid >> 4;
  const int c = tid & 15;
  const int row = blockIdx.x * 16 + r;
  if (row < M && c < DO) {
    const unsigned short* hp = &h16[(size_t)row * DM];
    float acc = 0.f;
    #pragma unroll 8
    for (int k = 0; k < DM; ++k) acc += bf2f(hp[k]) * Ws[k * DO + c];
    out[(size_t)row * DO + c] = acc + b[c];
  }
}

}  // namespace

extern "C" void kernel_launch(void* const* d_in, const int* in_sizes, int n_in,
                              void* d_out, int out_size, void* d_ws, size_t ws_size,
                              hipStream_t stream) {
  const float* x     = (const float*)d_in[0];
  const float* eattr = (const float*)d_in[1];
  const int*   eidx  = (const int*)d_in[2];
  const float* W_ne  = (const float*)d_in[3];
  const float* b_ne  = (const float*)d_in[4];
  const float* W_ee  = (const float*)d_in[5];
  const float* b_ee  = (const float*)d_in[6];
  const float* W_pre = (const float*)d_in[7];
  const float* b_pre = (const float*)d_in[8];
  const float* eps_a = (const float*)d_in[9];
  const float* W1_a  = (const float*)d_in[10];
  const float* b1_a  = (const float*)d_in[11];
  const float* W2_a  = (const float*)d_in[12];
  const float* b2_a  = (const float*)d_in[13];
  const float* eps_l = (const float*)d_in[14];
  const float* W1_l  = (const float*)d_in[15];
  const float* b1_l  = (const float*)d_in[16];
  const float* W2_l  = (const float*)d_in[17];
  const float* b2_l  = (const float*)d_in[18];
  const float* W_h   = (const float*)d_in[19];
  const float* b_h   = (const float*)d_in[20];

  const int* src = eidx;
  const int* dst = eidx + NE;

  // workspace layout (e8 LAST; fallback path needs none of it)
  char* wp = (char*)d_ws;
  unsigned short* h16   = (unsigned short*)wp; wp += (size_t)NN * DM * 2;
  unsigned short* t16   = (unsigned short*)wp; wp += (size_t)NN * DM * 2;
  unsigned short* agg16 = (unsigned short*)wp; wp += (size_t)NN * DM * 2;
  unsigned short* ea16  = (unsigned short*)wp; wp += (size_t)NE * DE * 2;
  unsigned short* wt_hi = (unsigned short*)wp; wp += WTOTAL * 2;
  unsigned short* wt_lo = (unsigned short*)wp; wp += WTOTAL * 2;
  unsigned short* wtee  = (unsigned short*)wp; wp += (size_t)DM * DE * 2;
  int* esrc    = (int*)wp;                     wp += (size_t)NE * 4;
  int* counts  = (int*)wp;                     wp += (size_t)NN * 4;
  int* row_ptr = (int*)wp;                     wp += (size_t)(NN + 1) * 4;
  int* cursor  = (int*)wp;                     wp += (size_t)NN * 4;
  wp = (char*)(((uintptr_t)wp + 15) & ~(uintptr_t)15);
  unsigned char* e8 = (unsigned char*)wp;
  const size_t need_e8 = (size_t)(wp - (char*)d_ws) + (size_t)NE * DM;
  const bool use_e8 = ws_size >= need_e8;

  // ---- CSR build ----
  hipMemsetAsync(counts, 0, NN * sizeof(int), stream);
  hist_kernel<<<(NE + 255) / 256, 256, 0, stream>>>(dst, counts, NE);
  scan_kernel<<<1, 1024, 0, stream>>>(counts, row_ptr, cursor, NN);
  scatter_kernel<<<(NE + 255) / 256, 256, 0, stream>>>(
      src, dst, eattr, cursor, esrc, ea16, NE);

  // ---- weight preprocessing ----
  convertW_kernel<<<dim3(16, 12), 256, 0, stream>>>(
      W_ne, W_pre, W1_a, W2_a, W1_l, W2_l, wt_hi, wt_lo);
  convertWee_kernel<<<1, 256, 0, stream>>>(W_ee, wtee);

  // ---- edge encoder (layer-invariant), once ----
  if (use_e8)
    eenc_kernel<<<dim3(NE / 128, 2), 256, 0, stream>>>(ea16, wtee, b_ee, e8);

  const dim3 mmgrid((NN + 63) / 64, 2);

  // encoder: t16 = x @ W_ne + b_ne   (K=64, fp32 A)
  mm_mfma<false, false, false><<<mmgrid, 256, 0, stream>>>(
      x, nullptr, wt_hi + woff(0), wt_lo + woff(0), b_ne, t16, NN, DI);
  // pre-MP: h16 = relu(t16 @ W_pre + b_pre)
  mm_mfma<true, false, true><<<mmgrid, 256, 0, stream>>>(
      nullptr, t16, wt_hi + woff(1), wt_lo + woff(1), b_pre, h16, NN, DM);

  for (int layer = 0; layer < 5; ++layer) {
    const float* eps; int ei; const float *b1, *b2; size_t o1, o2; bool resid;
    if (layer == 0) {
      eps = eps_a; ei = 0; b1 = b1_a; b2 = b2_a;
      o1 = woff(2); o2 = woff(3); resid = false;
    } else {
      const int i = layer - 1;
      eps = eps_l; ei = i;
      b1 = b1_l + (size_t)i * DM; b2 = b2_l + (size_t)i * DM;
      o1 = woff(4 + i); o2 = woff(8 + i); resid = true;
    }
    if (use_e8)
      gather_e8_kernel<<<5000, 256, 0, stream>>>(
          h16, row_ptr, esrc, e8, eps, ei, agg16, NN);
    else
      gather_rc_kernel<<<1280, 256, 0, stream>>>(
          h16, row_ptr, esrc, ea16, W_ee, b_ee, eps, ei, agg16, NN);
    // t16 = relu(agg16 @ W1 + b1)
    mm_mfma<true, false, true><<<mmgrid, 256, 0, stream>>>(
        nullptr, agg16, wt_hi + o1, wt_lo + o1, b1, t16, NN, DM);
    // h16 = [h16 +] t16 @ W2 + b2
    if (resid)
      mm_mfma<false, true, true><<<mmgrid, 256, 0, stream>>>(
          nullptr, t16, wt_hi + o2, wt_lo + o2, b2, h16, NN, DM);
    else
      mm_mfma<false, false, true><<<mmgrid, 256, 0, stream>>>(
          nullptr, t16, wt_hi + o2, wt_lo + o2, b2, h16, NN, DM);
  }

  head_kernel<<<(NN + 15) / 16, 256, 0, stream>>>(h16, W_h, b_h, (float*)d_out, NN);
}